// Round 1
// baseline (269.727 us; speedup 1.0000x reference)
//
#include <hip/hip_runtime.h>

#define NE 8
#define NH 1024
#define NI 1024
#define NGU 2048
#define MTOK 2048
#define TSLOT 4096

#define MAXT64 80     // slow path: 64-row tiles
#define MAXT128 40    // fast path: 128-row tiles

typedef short s16x8 __attribute__((ext_vector_type(8)));
typedef float f32x4 __attribute__((ext_vector_type(4)));
typedef unsigned short u16;

// ---- ws layout (bytes) ----
#define WS_SEG      0
#define WS_DESC64   64
#define WS_DESC128  384
#define WS_SLOT     1024          // 4096 ints -> 17408
#define WS_POS      17408         // 4096 ints -> 33792
#define WS_INTER    33792         // bf16 [4096][1024] -> +8388608 = 8422400
#define WS_AREG     8422400UL     // A_sorted bf16 [4096][1024] (8.39MB)
#define WS_NEED_FAST 16811008UL

__device__ inline u16 f2bf(float f) {
    unsigned u = __builtin_bit_cast(unsigned, f);
    u += 0x7fffu + ((u >> 16) & 1u);
    return (u16)(u >> 16);
}

// RNE pack of two fp32 -> 2x bf16 (lo = first operand), single HW instr
__device__ inline unsigned cvt_pk_bf16(float lo, float hi) {
    unsigned r;
    asm("v_cvt_pk_bf16_f32 %0, %1, %2" : "=v"(r) : "v"(lo), "v"(hi));
    return r;
}

__device__ inline void lds_dma16(const u16* g, u16* l) {
    __builtin_amdgcn_global_load_lds(
        (const __attribute__((address_space(1))) unsigned int*)g,
        (__attribute__((address_space(3))) unsigned int*)l, 16, 0, 0);
}

// swizzled LDS byte offset: row-stride 128B (64 bf16), 16B chunks XORed by row&7
__device__ inline int lds_off(int row, int blk) {
    return (row << 7) | (((blk ^ (row & 7)) & 7) << 4);
}

// ---- B-tile staging: 64k x 64n fp32 tile (K-major, row stride N) -> Bs bf16,
// n-major rows with the SAME chunk swizzle lds_off() expects on reads.
// Lane map chosen so each u32 LDS write instruction hits 32 distinct banks
// (2 lanes/bank = free): bank bits = {l0,l1, l2^i0, l3^i1, l4}.
template<int N>
__device__ inline void stageB(const float* __restrict__ wt, u16* __restrict__ Bs, int tid) {
    int lane = tid & 63, w = tid >> 6;
    int kr = 2 * (lane & 3) + 8 * ((lane >> 2) & 3);   // even k in [0,32)
    int nc = ((lane >> 4) << 2) + (w << 4);            // n base, multiple of 4
    const float* r0 = wt + (size_t)kr * N + nc;
    float4 v0 = *(const float4*)r0;                    // row kr
    float4 v1 = *(const float4*)(r0 + N);              // row kr+1
    const float* r1 = r0 + (size_t)32 * N;
    float4 v2 = *(const float4*)r1;                    // row kr+32
    float4 v3 = *(const float4*)(r1 + N);              // row kr+33
    int c0 = kr >> 3, kb2 = (kr & 7) << 1;
#pragma unroll
    for (int i = 0; i < 4; ++i) {
        int n = nc + i;
        unsigned pk0 = cvt_pk_bf16(((const float*)&v0)[i], ((const float*)&v1)[i]);
        *(unsigned*)((char*)Bs + (n << 7) + (((c0 ^ (n & 7)) & 7) << 4) + kb2) = pk0;
        unsigned pk1 = cvt_pk_bf16(((const float*)&v2)[i], ((const float*)&v3)[i]);
        *(unsigned*)((char*)Bs + (n << 7) + ((((c0 + 4) ^ (n & 7)) & 7) << 4) + kb2) = pk1;
    }
}

// ---------------- kernel 1: expert-sort + tile descriptors ----------------
__global__ void k_build(const int* __restrict__ ridx, int* __restrict__ seg,
                        int* __restrict__ d64, int* __restrict__ d128,
                        int* __restrict__ slot_of, int* __restrict__ pos_of) {
    __shared__ int cnt[NE];
    __shared__ int cur[NE];
    int tid = threadIdx.x;
    if (tid < NE) cnt[tid] = 0;
    __syncthreads();
    for (int s = tid; s < TSLOT; s += blockDim.x) atomicAdd(&cnt[ridx[s] & 7], 1);
    __syncthreads();
    if (tid == 0) {
        int a = 0;
        for (int e = 0; e < NE; ++e) { seg[e] = a; cur[e] = a; a += cnt[e]; }
        seg[NE] = a;
        int nt = 0;
        for (int e = 0; e < NE; ++e)
            for (int m0 = 0; m0 < cnt[e]; m0 += 64) d64[nt++] = (e << 16) | (m0 / 64);
        for (; nt < MAXT64; ++nt) d64[nt] = -1;
        nt = 0;
        for (int e = 0; e < NE; ++e)
            for (int m0 = 0; m0 < cnt[e]; m0 += 128) d128[nt++] = (e << 16) | (m0 / 128);
        for (; nt < MAXT128; ++nt) d128[nt] = -1;
    }
    __syncthreads();
    for (int s = tid; s < TSLOT; s += blockDim.x) {
        int e = ridx[s] & 7;
        int p = atomicAdd(&cur[e], 1);
        slot_of[p] = s;
        pos_of[s] = p;
    }
}

// ---------------- gather x rows into expert-sorted bf16 A ----------------
__global__ __launch_bounds__(256) void k_gather(const float* __restrict__ x,
                                                const int* __restrict__ slot_of,
                                                u16* __restrict__ A) {
    int r = blockIdx.x;
    int token = slot_of[r] >> 1;
    float4 v = ((const float4*)(x + (size_t)token * NH))[threadIdx.x];
    ushort4 o;
    o.x = f2bf(v.x); o.y = f2bf(v.y); o.z = f2bf(v.z); o.w = f2bf(v.w);
    ((ushort4*)(A + (size_t)r * NH))[threadIdx.x] = o;
}

// ---------------- fast gate_up: 128x64 tile, A via DMA, B reg-staged from fp32 ----
__global__ __launch_bounds__(256) void k_gateup_f(
        const u16* __restrict__ A,       // [TSLOT][NH] bf16, expert-sorted
        const float* __restrict__ W,     // [NE][NH][NGU] fp32 (K-major!)
        const float* __restrict__ bias,  // [NE][NGU]
        const int* __restrict__ seg, const int* __restrict__ desc,
        u16* __restrict__ inter) {       // [TSLOT][NI] bf16
    int d = desc[blockIdx.x];
    if (d < 0) return;
    int e = d >> 16, mt = d & 0xffff;
    int seg0 = seg[e], Te = seg[e + 1] - seg0, m0 = mt * 128;

    __shared__ __align__(16) u16 As[128 * 64];
    __shared__ __align__(16) u16 Bs[64 * 64];

    int tid = threadIdx.x;
    int lane = tid & 63, w = tid >> 6;
    int ml = lane & 15, kq = lane >> 4;
    int wm = w >> 1, wn = w & 1;
    int n0 = blockIdx.y * 64;
    const float* we = W + (size_t)e * NH * NGU;
    int dr = lane >> 3, db = (lane & 7) ^ dr;

    f32x4 zero = {0.f, 0.f, 0.f, 0.f};
    f32x4 acc[4][2];
#pragma unroll
    for (int i = 0; i < 4; ++i) { acc[i][0] = zero; acc[i][1] = zero; }

    for (int kb = 0; kb < NH; kb += 64) {
        __syncthreads();
#pragma unroll
        for (int c = 0; c < 4; ++c) {
            int gr = seg0 + m0 + c * 32 + w * 8 + dr;
            if (gr > TSLOT - 1) gr = TSLOT - 1;          // clamp (pad-free ws)
            lds_dma16(A + (size_t)gr * NH + kb + db * 8, As + c * 2048 + w * 512);
        }
        stageB<NGU>(we + (size_t)kb * NGU + n0, Bs, tid);
        __syncthreads();

#pragma unroll
        for (int kk = 0; kk < 64; kk += 32) {
            s16x8 af[4], bf[2];
#pragma unroll
            for (int i = 0; i < 4; ++i)
                af[i] = *(const s16x8*)((char*)As + lds_off(wm * 64 + i * 16 + ml, (kk >> 3) + kq));
#pragma unroll
            for (int i = 0; i < 2; ++i)
                bf[i] = *(const s16x8*)((char*)Bs + lds_off(wn * 32 + i * 16 + ml, (kk >> 3) + kq));
#pragma unroll
            for (int mi = 0; mi < 4; ++mi)
#pragma unroll
                for (int ni = 0; ni < 2; ++ni)
                    acc[mi][ni] = __builtin_amdgcn_mfma_f32_16x16x32_bf16(
                        af[mi], bf[ni], acc[mi][ni], 0, 0, 0);
        }
    }

#pragma unroll
    for (int ni = 0; ni < 2; ++ni) {
        int n = n0 + wn * 32 + ni * 16 + ml;
        float bv = bias[e * NGU + n];
#pragma unroll
        for (int mi = 0; mi < 4; ++mi) {
#pragma unroll
            for (int r = 0; r < 4; ++r) {
                float v = acc[mi][ni][r] + bv;
                float pr = __shfl_xor(v, 1, 64);
                float g = (lane & 1) ? pr : v;
                float u = (lane & 1) ? v : pr;
                g = fminf(g, 7.0f);
                u = fminf(fmaxf(u, -7.0f), 7.0f);
                float glu = g / (1.0f + __expf(-1.702f * g));
                float y = (u + 1.0f) * glu;
                int mloc = wm * 64 + mi * 16 + kq * 4 + r;
                if (!(lane & 1) && (m0 + mloc) < Te)
                    inter[(size_t)(seg0 + m0 + mloc) * NI + (n >> 1)] = f2bf(y);
            }
        }
    }
}

// ---------------- fast down: 128x64 tile, full-K, fused weighted atomic scatter ----
__global__ __launch_bounds__(256) void k_down_f(
        const u16* __restrict__ inter,   // [TSLOT][NI] bf16
        const float* __restrict__ W,     // [NE][NI][NH] fp32 (K-major!)
        const float* __restrict__ bias,  // [NE][NH]
        const float* __restrict__ rw,    // [MTOK][NE]
        const int* __restrict__ seg, const int* __restrict__ desc,
        const int* __restrict__ slot_of,
        float* __restrict__ out) {       // [MTOK][NH] fp32 (pre-zeroed)
    int d = desc[blockIdx.x];
    if (d < 0) return;
    int e = d >> 16, mt = d & 0xffff;
    int seg0 = seg[e], Te = seg[e + 1] - seg0, m0 = mt * 128;

    __shared__ __align__(16) u16 As[128 * 64];
    __shared__ __align__(16) u16 Bs[64 * 64];
    __shared__ int tokS[128];
    __shared__ float wgtS[128];

    int tid = threadIdx.x;
    if (tid < 128) {
        int m = m0 + tid;
        if (m < Te) {
            int token = slot_of[seg0 + m] >> 1;
            tokS[tid] = token;
            wgtS[tid] = rw[token * NE + e];
        } else {
            tokS[tid] = 0;
            wgtS[tid] = 0.0f;
        }
    }

    int lane = tid & 63, w = tid >> 6;
    int ml = lane & 15, kq = lane >> 4;
    int wm = w >> 1, wn = w & 1;
    int n0 = blockIdx.y * 64;
    const float* we = W + (size_t)e * NI * NH;
    int dr = lane >> 3, db = (lane & 7) ^ dr;

    f32x4 zero = {0.f, 0.f, 0.f, 0.f};
    f32x4 acc[4][2];
#pragma unroll
    for (int i = 0; i < 4; ++i) { acc[i][0] = zero; acc[i][1] = zero; }

    for (int kb = 0; kb < NI; kb += 64) {
        __syncthreads();
#pragma unroll
        for (int c = 0; c < 4; ++c) {
            int gr = seg0 + m0 + c * 32 + w * 8 + dr;
            if (gr > TSLOT - 1) gr = TSLOT - 1;          // clamp (pad-free ws)
            lds_dma16(inter + (size_t)gr * NI + kb + db * 8, As + c * 2048 + w * 512);
        }
        stageB<NH>(we + (size_t)kb * NH + n0, Bs, tid);
        __syncthreads();

#pragma unroll
        for (int kk = 0; kk < 64; kk += 32) {
            s16x8 af[4], bf[2];
#pragma unroll
            for (int i = 0; i < 4; ++i)
                af[i] = *(const s16x8*)((char*)As + lds_off(wm * 64 + i * 16 + ml, (kk >> 3) + kq));
#pragma unroll
            for (int i = 0; i < 2; ++i)
                bf[i] = *(const s16x8*)((char*)Bs + lds_off(wn * 32 + i * 16 + ml, (kk >> 3) + kq));
#pragma unroll
            for (int mi = 0; mi < 4; ++mi)
#pragma unroll
                for (int ni = 0; ni < 2; ++ni)
                    acc[mi][ni] = __builtin_amdgcn_mfma_f32_16x16x32_bf16(
                        af[mi], bf[ni], acc[mi][ni], 0, 0, 0);
        }
    }

    float bv[2];
#pragma unroll
    for (int ni = 0; ni < 2; ++ni)
        bv[ni] = bias[e * NH + n0 + wn * 32 + ni * 16 + ml];

#pragma unroll
    for (int mi = 0; mi < 4; ++mi) {
#pragma unroll
        for (int r = 0; r < 4; ++r) {
            int mloc = wm * 64 + mi * 16 + kq * 4 + r;
            if ((m0 + mloc) < Te) {
                int token = tokS[mloc];
                float wgt = wgtS[mloc];
#pragma unroll
                for (int ni = 0; ni < 2; ++ni) {
                    int n = n0 + wn * 32 + ni * 16 + ml;
                    atomicAdd(&out[(size_t)token * NH + n], (acc[mi][ni][r] + bv[ni]) * wgt);
                }
            }
        }
    }
}

// ---------------- slow-path kernels (round-2, proven) ----------------
__global__ __launch_bounds__(256) void k_gateup_s(
        const float* __restrict__ x, const float* __restrict__ w,
        const float* __restrict__ bias,
        const int* __restrict__ seg, const int* __restrict__ desc,
        const int* __restrict__ slot_of, u16* __restrict__ inter) {
    int d = desc[blockIdx.x];
    if (d < 0) return;
    int e = d >> 16, mt = d & 0xffff;
    int seg0 = seg[e], Te = seg[e + 1] - seg0, m0 = mt * 64;
    __shared__ u16 As[64 * 40];
    __shared__ int tok[64];
    int tid = threadIdx.x;
    if (tid < 64) {
        int m = m0 + tid;
        tok[tid] = (m < Te) ? (slot_of[seg0 + m] >> 1) : -1;
    }
    __syncthreads();
    int lane = tid & 63, wave = tid >> 6;
    int arow = tid >> 2, acol = (tid & 3) * 8;
    int ta = tok[arow];
    int kq = lane >> 4, ml = lane & 15;
    int nb = blockIdx.y * 128 + wave * 32;
    const float* wp = w + (size_t)e * NH * NGU;
    f32x4 zero = {0.f, 0.f, 0.f, 0.f};
    f32x4 acc[4][2];
#pragma unroll
    for (int i = 0; i < 4; ++i) { acc[i][0] = zero; acc[i][1] = zero; }
    for (int kb = 0; kb < NH; kb += 32) {
        float4 a0 = {0, 0, 0, 0}, a1 = {0, 0, 0, 0};
        if (ta >= 0) {
            const float* xp = x + (size_t)ta * NH + kb + acol;
            a0 = *(const float4*)xp; a1 = *(const float4*)(xp + 4);
        }
        s16x8 av;
        av[0] = (short)f2bf(a0.x); av[1] = (short)f2bf(a0.y);
        av[2] = (short)f2bf(a0.z); av[3] = (short)f2bf(a0.w);
        av[4] = (short)f2bf(a1.x); av[5] = (short)f2bf(a1.y);
        av[6] = (short)f2bf(a1.z); av[7] = (short)f2bf(a1.w);
        __syncthreads();
        *(s16x8*)&As[arow * 40 + acol] = av;
        __syncthreads();
        s16x8 afr[4];
#pragma unroll
        for (int msi = 0; msi < 4; ++msi)
            afr[msi] = *(const s16x8*)&As[(msi * 16 + ml) * 40 + kq * 8];
        s16x8 bfr[2];
#pragma unroll
        for (int s = 0; s < 2; ++s) {
            const float* bp = wp + (size_t)(kb + kq * 8) * NGU + nb + s * 16 + ml;
#pragma unroll
            for (int j = 0; j < 8; ++j) bfr[s][j] = (short)f2bf(bp[(size_t)j * NGU]);
        }
#pragma unroll
        for (int msi = 0; msi < 4; ++msi)
#pragma unroll
            for (int s = 0; s < 2; ++s)
                acc[msi][s] = __builtin_amdgcn_mfma_f32_16x16x32_bf16(
                    afr[msi], bfr[s], acc[msi][s], 0, 0, 0);
    }
#pragma unroll
    for (int s = 0; s < 2; ++s) {
        int n = nb + s * 16 + ml;
        float bv = bias[e * NGU + n];
#pragma unroll
        for (int msi = 0; msi < 4; ++msi) {
#pragma unroll
            for (int r = 0; r < 4; ++r) {
                float v = acc[msi][s][r] + bv;
                float pr = __shfl_xor(v, 1, 64);
                float g = (lane & 1) ? pr : v;
                float u = (lane & 1) ? v : pr;
                g = fminf(g, 7.0f);
                u = fminf(fmaxf(u, -7.0f), 7.0f);
                float glu = g / (1.0f + __expf(-1.702f * g));
                float y = (u + 1.0f) * glu;
                int mrow = m0 + msi * 16 + kq * 4 + r;
                if (!(lane & 1) && mrow < Te)
                    inter[(size_t)(seg0 + mrow) * NI + (n >> 1)] = f2bf(y);
            }
        }
    }
}

__global__ __launch_bounds__(256) void k_down_s(
        const u16* __restrict__ inter, const float* __restrict__ w,
        const float* __restrict__ bias, const float* __restrict__ rw,
        const int* __restrict__ seg, const int* __restrict__ desc,
        const int* __restrict__ slot_of, float* __restrict__ out) {
    int d = desc[blockIdx.x];
    if (d < 0) return;
    int e = d >> 16, mt = d & 0xffff;
    int seg0 = seg[e], Te = seg[e + 1] - seg0, m0 = mt * 64;
    __shared__ u16 As[64 * 40];
    int tid = threadIdx.x;
    int lane = tid & 63, wave = tid >> 6;
    int arow = tid >> 2, acol = (tid & 3) * 8;
    bool avalid = (m0 + arow) < Te;
    int kq = lane >> 4, ml = lane & 15;
    int nb = blockIdx.y * 128 + wave * 32;
    const float* wp = w + (size_t)e * NI * NH;
    f32x4 zero = {0.f, 0.f, 0.f, 0.f};
    f32x4 acc[4][2];
#pragma unroll
    for (int i = 0; i < 4; ++i) { acc[i][0] = zero; acc[i][1] = zero; }
    for (int kb = 0; kb < NI; kb += 32) {
        s16x8 av = {0, 0, 0, 0, 0, 0, 0, 0};
        if (avalid) av = *(const s16x8*)(inter + (size_t)(seg0 + m0 + arow) * NI + kb + acol);
        __syncthreads();
        *(s16x8*)&As[arow * 40 + acol] = av;
        __syncthreads();
        s16x8 afr[4];
#pragma unroll
        for (int msi = 0; msi < 4; ++msi)
            afr[msi] = *(const s16x8*)&As[(msi * 16 + ml) * 40 + kq * 8];
        s16x8 bfr[2];
#pragma unroll
        for (int s = 0; s < 2; ++s) {
            const float* bp = wp + (size_t)(kb + kq * 8) * NH + nb + s * 16 + ml;
#pragma unroll
            for (int j = 0; j < 8; ++j) bfr[s][j] = (short)f2bf(bp[(size_t)j * NH]);
        }
#pragma unroll
        for (int msi = 0; msi < 4; ++msi)
#pragma unroll
            for (int s = 0; s < 2; ++s)
                acc[msi][s] = __builtin_amdgcn_mfma_f32_16x16x32_bf16(
                    afr[msi], bfr[s], acc[msi][s], 0, 0, 0);
    }
    float bv[2];
    bv[0] = bias[e * NH + nb + ml];
    bv[1] = bias[e * NH + nb + 16 + ml];
#pragma unroll
    for (int msi = 0; msi < 4; ++msi) {
#pragma unroll
        for (int r = 0; r < 4; ++r) {
            int mrow = m0 + msi * 16 + kq * 4 + r;
            if (mrow < Te) {
                int slot = slot_of[seg0 + mrow];
                int token = slot >> 1;
                float wgt = rw[token * NE + e];
#pragma unroll
                for (int s = 0; s < 2; ++s) {
                    int n = nb + s * 16 + ml;
                    atomicAdd(&out[(size_t)token * NH + n], (acc[msi][s][r] + bv[s]) * wgt);
                }
            }
        }
    }
}

extern "C" void kernel_launch(void* const* d_in, const int* in_sizes, int n_in,
                              void* d_out, int out_size, void* d_ws, size_t ws_size,
                              hipStream_t stream) {
    const float* x   = (const float*)d_in[0];
    const int*   ri  = (const int*)d_in[1];
    const float* rw  = (const float*)d_in[2];
    const float* wgu = (const float*)d_in[3];
    const float* bgu = (const float*)d_in[4];
    const float* wd  = (const float*)d_in[5];
    const float* bd  = (const float*)d_in[6];
    float* out = (float*)d_out;

    char* ws = (char*)d_ws;
    int* seg     = (int*)(ws + WS_SEG);
    int* d64     = (int*)(ws + WS_DESC64);
    int* d128    = (int*)(ws + WS_DESC128);
    int* slot_of = (int*)(ws + WS_SLOT);
    int* pos_of  = (int*)(ws + WS_POS);
    u16* inter   = (u16*)(ws + WS_INTER);

    hipLaunchKernelGGL(k_build, dim3(1), dim3(256), 0, stream, ri, seg, d64, d128,
                       slot_of, pos_of);
    hipMemsetAsync(out, 0, (size_t)MTOK * NH * sizeof(float), stream);

    if (ws_size >= WS_NEED_FAST) {
        u16* aReg = (u16*)(ws + WS_AREG);
        hipLaunchKernelGGL(k_gather, dim3(TSLOT), dim3(256), 0, stream, x, slot_of, aReg);
        hipLaunchKernelGGL(k_gateup_f, dim3(MAXT128, NGU / 64), dim3(256), 0, stream,
                           aReg, wgu, bgu, seg, d128, inter);
        hipLaunchKernelGGL(k_down_f, dim3(MAXT128, NH / 64), dim3(256), 0, stream,
                           inter, wd, bd, rw, seg, d128, slot_of, out);
    } else {
        hipLaunchKernelGGL(k_gateup_s, dim3(MAXT64, NGU / 128), dim3(256), 0, stream,
                           x, wgu, bgu, seg, d64, slot_of, inter);
        hipLaunchKernelGGL(k_down_s, dim3(MAXT64, NH / 128), dim3(256), 0, stream,
                           inter, wd, bd, rw, seg, d64, slot_of, out);
    }
}

// Round 2
// 251.776 us; speedup vs baseline: 1.0713x; 1.0713x over previous
//
#include <hip/hip_runtime.h>

#define NE 8
#define NH 1024
#define NI 1024
#define NGU 2048
#define MTOK 2048
#define TSLOT 4096

#define MAXT64 80     // slow path: 64-row tiles
#define MAXT128 40    // fast path: 128-row tiles

typedef short s16x8 __attribute__((ext_vector_type(8)));
typedef float f32x4 __attribute__((ext_vector_type(4)));
typedef unsigned short u16;

// ---- ws layout (bytes) ----
#define WS_SEG      0
#define WS_DESC64   64
#define WS_DESC128  384
#define WS_SLOT     1024          // 4096 ints -> 17408
#define WS_POS      17408         // 4096 ints -> 33792
#define WS_INTER    33792         // bf16 [4096][1024] -> +8388608 = 8422400
#define WS_AREG     8422400UL     // A_sorted bf16 [4096][1024] (8.39MB)
#define WS_WREG     25199616UL    // WT_gu bf16 (33.55MB); later overwritten by WT_d (16.78MB)
#define WS_NEED_FAST 58754048UL

__device__ inline u16 f2bf(float f) {
    unsigned u = __builtin_bit_cast(unsigned, f);
    u += 0x7fffu + ((u >> 16) & 1u);
    return (u16)(u >> 16);
}

__device__ inline void lds_dma16(const u16* g, u16* l) {
    __builtin_amdgcn_global_load_lds(
        (const __attribute__((address_space(1))) unsigned int*)g,
        (__attribute__((address_space(3))) unsigned int*)l, 16, 0, 0);
}

// swizzled LDS byte offset: row-stride 128B (64 bf16), 16B chunks XORed by row&7
__device__ inline int lds_off(int row, int blk) {
    return (row << 7) | (((blk ^ (row & 7)) & 7) << 4);
}

// ---------------- kernel 1: expert-sort + tile descriptors ----------------
__global__ void k_build(const int* __restrict__ ridx, int* __restrict__ seg,
                        int* __restrict__ d64, int* __restrict__ d128,
                        int* __restrict__ slot_of, int* __restrict__ pos_of) {
    __shared__ int cnt[NE];
    __shared__ int cur[NE];
    int tid = threadIdx.x;
    if (tid < NE) cnt[tid] = 0;
    __syncthreads();
    for (int s = tid; s < TSLOT; s += blockDim.x) atomicAdd(&cnt[ridx[s] & 7], 1);
    __syncthreads();
    if (tid == 0) {
        int a = 0;
        for (int e = 0; e < NE; ++e) { seg[e] = a; cur[e] = a; a += cnt[e]; }
        seg[NE] = a;
        int nt = 0;
        for (int e = 0; e < NE; ++e)
            for (int m0 = 0; m0 < cnt[e]; m0 += 64) d64[nt++] = (e << 16) | (m0 / 64);
        for (; nt < MAXT64; ++nt) d64[nt] = -1;
        nt = 0;
        for (int e = 0; e < NE; ++e)
            for (int m0 = 0; m0 < cnt[e]; m0 += 128) d128[nt++] = (e << 16) | (m0 / 128);
        for (; nt < MAXT128; ++nt) d128[nt] = -1;
    }
    __syncthreads();
    for (int s = tid; s < TSLOT; s += blockDim.x) {
        int e = ridx[s] & 7;
        int p = atomicAdd(&cur[e], 1);
        slot_of[p] = s;
        pos_of[s] = p;
    }
}

// ---------------- gather x rows into expert-sorted bf16 A ----------------
__global__ __launch_bounds__(256) void k_gather(const float* __restrict__ x,
                                                const int* __restrict__ slot_of,
                                                u16* __restrict__ A) {
    int r = blockIdx.x;
    int token = slot_of[r] >> 1;
    float4 v = ((const float4*)(x + (size_t)token * NH))[threadIdx.x];
    ushort4 o;
    o.x = f2bf(v.x); o.y = f2bf(v.y); o.z = f2bf(v.z); o.w = f2bf(v.w);
    ((ushort4*)(A + (size_t)r * NH))[threadIdx.x] = o;
}

// ---------------- transpose+convert: W[e][K][N] fp32 -> WT[e][N][K] bf16 ----------------
// LDS T stride 66 u16 (132B): odd half-stride -> consecutive n hit distinct banks.
__global__ __launch_bounds__(256) void k_tr(const float* __restrict__ W,
                                            u16* __restrict__ WT, int K, int N) {
    __shared__ u16 T[64][66];
    int tid = threadIdx.x;
    const float* in = W + (size_t)blockIdx.z * K * N;
    u16* out = WT + (size_t)blockIdx.z * N * K;
    int n0 = blockIdx.x * 64, k0 = blockIdx.y * 64;
#pragma unroll
    for (int p = 0; p < 2; ++p) {
        int kr = p * 32 + (tid >> 4) * 2;      // even k row
        int nc = (tid & 15) * 4;
        const float* r0 = in + (size_t)(k0 + kr) * N + n0 + nc;
        float4 v0 = *(const float4*)r0;
        float4 v1 = *(const float4*)(r0 + N);
#pragma unroll
        for (int i = 0; i < 4; ++i) {
            unsigned lo = f2bf(((const float*)&v0)[i]);
            unsigned hi = f2bf(((const float*)&v1)[i]);
            *(unsigned*)&T[nc + i][kr] = lo | (hi << 16);
        }
    }
    __syncthreads();
#pragma unroll
    for (int p = 0; p < 2; ++p) {
        int idx = p * 256 + tid;
        int nr = idx >> 3, kc = (idx & 7) * 8;
        unsigned q0 = *(const unsigned*)&T[nr][kc + 0];
        unsigned q1 = *(const unsigned*)&T[nr][kc + 2];
        unsigned q2 = *(const unsigned*)&T[nr][kc + 4];
        unsigned q3 = *(const unsigned*)&T[nr][kc + 6];
        uint4 vv = {q0, q1, q2, q3};
        *(uint4*)(out + (size_t)(n0 + nr) * K + k0 + kc) = vv;
    }
}

// ---------------- fast gate_up: 128x128 tile, all-DMA staging ----------------
__global__ __launch_bounds__(256) void k_gateup_f(
        const u16* __restrict__ A,       // [TSLOT][NH] bf16, expert-sorted
        const u16* __restrict__ wt,      // [NE][NGU][NH] bf16 (n-major)
        const float* __restrict__ bias,  // [NE][NGU]
        const int* __restrict__ seg, const int* __restrict__ desc,
        u16* __restrict__ inter) {       // [TSLOT][NI] bf16
    int d = desc[blockIdx.x];
    if (d < 0) return;
    int e = d >> 16, mt = d & 0xffff;
    int seg0 = seg[e], Te = seg[e + 1] - seg0, m0 = mt * 128;

    __shared__ __align__(16) u16 As[128 * 64];
    __shared__ __align__(16) u16 Bs[128 * 64];

    int tid = threadIdx.x;
    int lane = tid & 63, w = tid >> 6;
    int ml = lane & 15, kq = lane >> 4;
    int wm = w >> 1, wn = w & 1;
    int n0 = blockIdx.y * 128;
    const u16* wte = wt + (size_t)e * NGU * NH;
    int dr = lane >> 3, db = (lane & 7) ^ dr;

    f32x4 zero = {0.f, 0.f, 0.f, 0.f};
    f32x4 acc[4][4];
#pragma unroll
    for (int i = 0; i < 4; ++i)
#pragma unroll
        for (int j = 0; j < 4; ++j) acc[i][j] = zero;

    for (int kb = 0; kb < NH; kb += 64) {
        __syncthreads();
#pragma unroll
        for (int c = 0; c < 4; ++c) {
            int gr = seg0 + m0 + c * 32 + w * 8 + dr;
            if (gr > TSLOT - 1) gr = TSLOT - 1;          // clamp (pad-free ws)
            lds_dma16(A + (size_t)gr * NH + kb + db * 8, As + c * 2048 + w * 512);
        }
#pragma unroll
        for (int c = 0; c < 4; ++c) {
            int row = c * 32 + w * 8 + dr;
            lds_dma16(wte + (size_t)(n0 + row) * NH + kb + db * 8, Bs + c * 2048 + w * 512);
        }
        __syncthreads();

#pragma unroll
        for (int kk = 0; kk < 64; kk += 32) {
            s16x8 af[4], bf[4];
#pragma unroll
            for (int i = 0; i < 4; ++i)
                af[i] = *(const s16x8*)((char*)As + lds_off(wm * 64 + i * 16 + ml, (kk >> 3) + kq));
#pragma unroll
            for (int i = 0; i < 4; ++i)
                bf[i] = *(const s16x8*)((char*)Bs + lds_off(wn * 64 + i * 16 + ml, (kk >> 3) + kq));
#pragma unroll
            for (int mi = 0; mi < 4; ++mi)
#pragma unroll
                for (int ni = 0; ni < 4; ++ni)
                    acc[mi][ni] = __builtin_amdgcn_mfma_f32_16x16x32_bf16(
                        af[mi], bf[ni], acc[mi][ni], 0, 0, 0);
        }
    }

#pragma unroll
    for (int ni = 0; ni < 4; ++ni) {
        int n = n0 + wn * 64 + ni * 16 + ml;
        float bv = bias[e * NGU + n];
#pragma unroll
        for (int mi = 0; mi < 4; ++mi) {
#pragma unroll
            for (int r = 0; r < 4; ++r) {
                float v = acc[mi][ni][r] + bv;
                float pr = __shfl_xor(v, 1, 64);
                float g = (lane & 1) ? pr : v;
                float u = (lane & 1) ? v : pr;
                g = fminf(g, 7.0f);
                u = fminf(fmaxf(u, -7.0f), 7.0f);
                float glu = g / (1.0f + __expf(-1.702f * g));
                float y = (u + 1.0f) * glu;
                int mloc = wm * 64 + mi * 16 + kq * 4 + r;
                if (!(lane & 1) && (m0 + mloc) < Te)
                    inter[(size_t)(seg0 + m0 + mloc) * NI + (n >> 1)] = f2bf(y);
            }
        }
    }
}

// ---------------- fast down: 128x128 tile, full-K, fused weighted atomic scatter ----
__global__ __launch_bounds__(256) void k_down_f(
        const u16* __restrict__ inter,   // [TSLOT][NI] bf16
        const u16* __restrict__ wt,      // [NE][NH][NI] bf16 (n-major)
        const float* __restrict__ bias,  // [NE][NH]
        const float* __restrict__ rw,    // [MTOK][NE]
        const int* __restrict__ seg, const int* __restrict__ desc,
        const int* __restrict__ slot_of,
        float* __restrict__ out) {       // [MTOK][NH] fp32 (pre-zeroed)
    int d = desc[blockIdx.x];
    if (d < 0) return;
    int e = d >> 16, mt = d & 0xffff;
    int seg0 = seg[e], Te = seg[e + 1] - seg0, m0 = mt * 128;

    __shared__ __align__(16) u16 As[128 * 64];
    __shared__ __align__(16) u16 Bs[128 * 64];
    __shared__ int tokS[128];
    __shared__ float wgtS[128];

    int tid = threadIdx.x;
    if (tid < 128) {
        int m = m0 + tid;
        if (m < Te) {
            int token = slot_of[seg0 + m] >> 1;
            tokS[tid] = token;
            wgtS[tid] = rw[token * NE + e];
        } else {
            tokS[tid] = 0;
            wgtS[tid] = 0.0f;
        }
    }

    int lane = tid & 63, w = tid >> 6;
    int ml = lane & 15, kq = lane >> 4;
    int wm = w >> 1, wn = w & 1;
    int n0 = blockIdx.y * 128;
    const u16* wte = wt + (size_t)e * NH * NI;
    int dr = lane >> 3, db = (lane & 7) ^ dr;

    f32x4 zero = {0.f, 0.f, 0.f, 0.f};
    f32x4 acc[4][4];
#pragma unroll
    for (int i = 0; i < 4; ++i)
#pragma unroll
        for (int j = 0; j < 4; ++j) acc[i][j] = zero;

    for (int kb = 0; kb < NI; kb += 64) {
        __syncthreads();
#pragma unroll
        for (int c = 0; c < 4; ++c) {
            int gr = seg0 + m0 + c * 32 + w * 8 + dr;
            if (gr > TSLOT - 1) gr = TSLOT - 1;          // clamp (pad-free ws)
            lds_dma16(inter + (size_t)gr * NI + kb + db * 8, As + c * 2048 + w * 512);
        }
#pragma unroll
        for (int c = 0; c < 4; ++c) {
            int row = c * 32 + w * 8 + dr;
            lds_dma16(wte + (size_t)(n0 + row) * NI + kb + db * 8, Bs + c * 2048 + w * 512);
        }
        __syncthreads();

#pragma unroll
        for (int kk = 0; kk < 64; kk += 32) {
            s16x8 af[4], bf[4];
#pragma unroll
            for (int i = 0; i < 4; ++i)
                af[i] = *(const s16x8*)((char*)As + lds_off(wm * 64 + i * 16 + ml, (kk >> 3) + kq));
#pragma unroll
            for (int i = 0; i < 4; ++i)
                bf[i] = *(const s16x8*)((char*)Bs + lds_off(wn * 64 + i * 16 + ml, (kk >> 3) + kq));
#pragma unroll
            for (int mi = 0; mi < 4; ++mi)
#pragma unroll
                for (int ni = 0; ni < 4; ++ni)
                    acc[mi][ni] = __builtin_amdgcn_mfma_f32_16x16x32_bf16(
                        af[mi], bf[ni], acc[mi][ni], 0, 0, 0);
        }
    }

    float bv[4];
#pragma unroll
    for (int ni = 0; ni < 4; ++ni)
        bv[ni] = bias[e * NH + n0 + wn * 64 + ni * 16 + ml];

#pragma unroll
    for (int mi = 0; mi < 4; ++mi) {
#pragma unroll
        for (int r = 0; r < 4; ++r) {
            int mloc = wm * 64 + mi * 16 + kq * 4 + r;
            if ((m0 + mloc) < Te) {
                int token = tokS[mloc];
                float wgt = wgtS[mloc];
#pragma unroll
                for (int ni = 0; ni < 4; ++ni) {
                    int n = n0 + wn * 64 + ni * 16 + ml;
                    atomicAdd(&out[(size_t)token * NH + n], (acc[mi][ni][r] + bv[ni]) * wgt);
                }
            }
        }
    }
}

// ---------------- slow-path kernels (round-2, proven) ----------------
__global__ __launch_bounds__(256) void k_gateup_s(
        const float* __restrict__ x, const float* __restrict__ w,
        const float* __restrict__ bias,
        const int* __restrict__ seg, const int* __restrict__ desc,
        const int* __restrict__ slot_of, u16* __restrict__ inter) {
    int d = desc[blockIdx.x];
    if (d < 0) return;
    int e = d >> 16, mt = d & 0xffff;
    int seg0 = seg[e], Te = seg[e + 1] - seg0, m0 = mt * 64;
    __shared__ u16 As[64 * 40];
    __shared__ int tok[64];
    int tid = threadIdx.x;
    if (tid < 64) {
        int m = m0 + tid;
        tok[tid] = (m < Te) ? (slot_of[seg0 + m] >> 1) : -1;
    }
    __syncthreads();
    int lane = tid & 63, wave = tid >> 6;
    int arow = tid >> 2, acol = (tid & 3) * 8;
    int ta = tok[arow];
    int kq = lane >> 4, ml = lane & 15;
    int nb = blockIdx.y * 128 + wave * 32;
    const float* wp = w + (size_t)e * NH * NGU;
    f32x4 zero = {0.f, 0.f, 0.f, 0.f};
    f32x4 acc[4][2];
#pragma unroll
    for (int i = 0; i < 4; ++i) { acc[i][0] = zero; acc[i][1] = zero; }
    for (int kb = 0; kb < NH; kb += 32) {
        float4 a0 = {0, 0, 0, 0}, a1 = {0, 0, 0, 0};
        if (ta >= 0) {
            const float* xp = x + (size_t)ta * NH + kb + acol;
            a0 = *(const float4*)xp; a1 = *(const float4*)(xp + 4);
        }
        s16x8 av;
        av[0] = (short)f2bf(a0.x); av[1] = (short)f2bf(a0.y);
        av[2] = (short)f2bf(a0.z); av[3] = (short)f2bf(a0.w);
        av[4] = (short)f2bf(a1.x); av[5] = (short)f2bf(a1.y);
        av[6] = (short)f2bf(a1.z); av[7] = (short)f2bf(a1.w);
        __syncthreads();
        *(s16x8*)&As[arow * 40 + acol] = av;
        __syncthreads();
        s16x8 afr[4];
#pragma unroll
        for (int msi = 0; msi < 4; ++msi)
            afr[msi] = *(const s16x8*)&As[(msi * 16 + ml) * 40 + kq * 8];
        s16x8 bfr[2];
#pragma unroll
        for (int s = 0; s < 2; ++s) {
            const float* bp = wp + (size_t)(kb + kq * 8) * NGU + nb + s * 16 + ml;
#pragma unroll
            for (int j = 0; j < 8; ++j) bfr[s][j] = (short)f2bf(bp[(size_t)j * NGU]);
        }
#pragma unroll
        for (int msi = 0; msi < 4; ++msi)
#pragma unroll
            for (int s = 0; s < 2; ++s)
                acc[msi][s] = __builtin_amdgcn_mfma_f32_16x16x32_bf16(
                    afr[msi], bfr[s], acc[msi][s], 0, 0, 0);
    }
#pragma unroll
    for (int s = 0; s < 2; ++s) {
        int n = nb + s * 16 + ml;
        float bv = bias[e * NGU + n];
#pragma unroll
        for (int msi = 0; msi < 4; ++msi) {
#pragma unroll
            for (int r = 0; r < 4; ++r) {
                float v = acc[msi][s][r] + bv;
                float pr = __shfl_xor(v, 1, 64);
                float g = (lane & 1) ? pr : v;
                float u = (lane & 1) ? v : pr;
                g = fminf(g, 7.0f);
                u = fminf(fmaxf(u, -7.0f), 7.0f);
                float glu = g / (1.0f + __expf(-1.702f * g));
                float y = (u + 1.0f) * glu;
                int mrow = m0 + msi * 16 + kq * 4 + r;
                if (!(lane & 1) && mrow < Te)
                    inter[(size_t)(seg0 + mrow) * NI + (n >> 1)] = f2bf(y);
            }
        }
    }
}

__global__ __launch_bounds__(256) void k_down_s(
        const u16* __restrict__ inter, const float* __restrict__ w,
        const float* __restrict__ bias, const float* __restrict__ rw,
        const int* __restrict__ seg, const int* __restrict__ desc,
        const int* __restrict__ slot_of, float* __restrict__ out) {
    int d = desc[blockIdx.x];
    if (d < 0) return;
    int e = d >> 16, mt = d & 0xffff;
    int seg0 = seg[e], Te = seg[e + 1] - seg0, m0 = mt * 64;
    __shared__ u16 As[64 * 40];
    int tid = threadIdx.x;
    int lane = tid & 63, wave = tid >> 6;
    int arow = tid >> 2, acol = (tid & 3) * 8;
    bool avalid = (m0 + arow) < Te;
    int kq = lane >> 4, ml = lane & 15;
    int nb = blockIdx.y * 128 + wave * 32;
    const float* wp = w + (size_t)e * NI * NH;
    f32x4 zero = {0.f, 0.f, 0.f, 0.f};
    f32x4 acc[4][2];
#pragma unroll
    for (int i = 0; i < 4; ++i) { acc[i][0] = zero; acc[i][1] = zero; }
    for (int kb = 0; kb < NI; kb += 32) {
        s16x8 av = {0, 0, 0, 0, 0, 0, 0, 0};
        if (avalid) av = *(const s16x8*)(inter + (size_t)(seg0 + m0 + arow) * NI + kb + acol);
        __syncthreads();
        *(s16x8*)&As[arow * 40 + acol] = av;
        __syncthreads();
        s16x8 afr[4];
#pragma unroll
        for (int msi = 0; msi < 4; ++msi)
            afr[msi] = *(const s16x8*)&As[(msi * 16 + ml) * 40 + kq * 8];
        s16x8 bfr[2];
#pragma unroll
        for (int s = 0; s < 2; ++s) {
            const float* bp = wp + (size_t)(kb + kq * 8) * NH + nb + s * 16 + ml;
#pragma unroll
            for (int j = 0; j < 8; ++j) bfr[s][j] = (short)f2bf(bp[(size_t)j * NH]);
        }
#pragma unroll
        for (int msi = 0; msi < 4; ++msi)
#pragma unroll
            for (int s = 0; s < 2; ++s)
                acc[msi][s] = __builtin_amdgcn_mfma_f32_16x16x32_bf16(
                    afr[msi], bfr[s], acc[msi][s], 0, 0, 0);
    }
    float bv[2];
    bv[0] = bias[e * NH + nb + ml];
    bv[1] = bias[e * NH + nb + 16 + ml];
#pragma unroll
    for (int msi = 0; msi < 4; ++msi) {
#pragma unroll
        for (int r = 0; r < 4; ++r) {
            int mrow = m0 + msi * 16 + kq * 4 + r;
            if (mrow < Te) {
                int slot = slot_of[seg0 + mrow];
                int token = slot >> 1;
                float wgt = rw[token * NE + e];
#pragma unroll
                for (int s = 0; s < 2; ++s) {
                    int n = nb + s * 16 + ml;
                    atomicAdd(&out[(size_t)token * NH + n], (acc[msi][s][r] + bv[s]) * wgt);
                }
            }
        }
    }
}

extern "C" void kernel_launch(void* const* d_in, const int* in_sizes, int n_in,
                              void* d_out, int out_size, void* d_ws, size_t ws_size,
                              hipStream_t stream) {
    const float* x   = (const float*)d_in[0];
    const int*   ri  = (const int*)d_in[1];
    const float* rw  = (const float*)d_in[2];
    const float* wgu = (const float*)d_in[3];
    const float* bgu = (const float*)d_in[4];
    const float* wd  = (const float*)d_in[5];
    const float* bd  = (const float*)d_in[6];
    float* out = (float*)d_out;

    char* ws = (char*)d_ws;
    int* seg     = (int*)(ws + WS_SEG);
    int* d64     = (int*)(ws + WS_DESC64);
    int* d128    = (int*)(ws + WS_DESC128);
    int* slot_of = (int*)(ws + WS_SLOT);
    int* pos_of  = (int*)(ws + WS_POS);
    u16* inter   = (u16*)(ws + WS_INTER);

    hipLaunchKernelGGL(k_build, dim3(1), dim3(256), 0, stream, ri, seg, d64, d128,
                       slot_of, pos_of);
    hipMemsetAsync(out, 0, (size_t)MTOK * NH * sizeof(float), stream);

    if (ws_size >= WS_NEED_FAST) {
        u16* aReg = (u16*)(ws + WS_AREG);
        u16* wReg = (u16*)(ws + WS_WREG);
        hipLaunchKernelGGL(k_tr, dim3(NGU / 64, NH / 64, NE), dim3(256), 0, stream,
                           wgu, wReg, NH, NGU);
        hipLaunchKernelGGL(k_gather, dim3(TSLOT), dim3(256), 0, stream, x, slot_of, aReg);
        hipLaunchKernelGGL(k_gateup_f, dim3(MAXT128, NGU / 128), dim3(256), 0, stream,
                           aReg, wReg, bgu, seg, d128, inter);
        hipLaunchKernelGGL(k_tr, dim3(NH / 64, NI / 64, NE), dim3(256), 0, stream,
                           wd, wReg, NI, NH);
        hipLaunchKernelGGL(k_down_f, dim3(MAXT128, NH / 128), dim3(256), 0, stream,
                           inter, wReg, bd, rw, seg, d128, slot_of, out);
    } else {
        hipLaunchKernelGGL(k_gateup_s, dim3(MAXT64, NGU / 128), dim3(256), 0, stream,
                           x, wgu, bgu, seg, d64, slot_of, inter);
        hipLaunchKernelGGL(k_down_s, dim3(MAXT64, NH / 128), dim3(256), 0, stream,
                           inter, wd, bd, rw, seg, d64, slot_of, out);
    }
}

// Round 3
// 248.344 us; speedup vs baseline: 1.0861x; 1.0138x over previous
//
#include <hip/hip_runtime.h>

#define NE 8
#define NH 1024
#define NI 1024
#define NGU 2048
#define MTOK 2048
#define TSLOT 4096

#define MAXT64 80     // slow path: 64-row tiles
#define MAXT128 40    // fast path: 128-row tiles

typedef short s16x8 __attribute__((ext_vector_type(8)));
typedef float f32x4 __attribute__((ext_vector_type(4)));
typedef unsigned short u16;

// ---- ws layout (bytes) ----
#define WS_SEG      0
#define WS_DESC64   64
#define WS_DESC128  384
#define WS_SLOT     1024          // 4096 ints -> 17408
#define WS_POS      17408         // 4096 ints -> 33792
#define WS_INTER    33792         // bf16 [4096][1024] -> +8388608 = 8422400
#define WS_AREG     8422400UL     // A_sorted bf16 [4096][1024] (8.39MB)
#define WS_WREG     25199616UL    // WT_gu bf16 (33.55MB); later overwritten by WT_d (16.78MB)
#define WS_NEED_FAST 58754048UL

__device__ inline u16 f2bf(float f) {
    unsigned u = __builtin_bit_cast(unsigned, f);
    u += 0x7fffu + ((u >> 16) & 1u);
    return (u16)(u >> 16);
}

__device__ inline void lds_dma16(const u16* g, u16* l) {
    __builtin_amdgcn_global_load_lds(
        (const __attribute__((address_space(1))) unsigned int*)g,
        (__attribute__((address_space(3))) unsigned int*)l, 16, 0, 0);
}

// swizzled LDS byte offset: row-stride 128B (64 bf16), 16B chunks XORed by row&7
__device__ inline int lds_off(int row, int blk) {
    return (row << 7) | (((blk ^ (row & 7)) & 7) << 4);
}

#define PIPE_FENCE asm volatile("" ::: "memory")
#define WAIT_VM6   asm volatile("s_waitcnt vmcnt(6)" ::: "memory")
#define WAIT_VM0   asm volatile("s_waitcnt vmcnt(0)" ::: "memory")

// ---------------- kernel 1: expert-sort + tile descriptors ----------------
__global__ void k_build(const int* __restrict__ ridx, int* __restrict__ seg,
                        int* __restrict__ d64, int* __restrict__ d128,
                        int* __restrict__ slot_of, int* __restrict__ pos_of) {
    __shared__ int cnt[NE];
    __shared__ int cur[NE];
    int tid = threadIdx.x;
    if (tid < NE) cnt[tid] = 0;
    __syncthreads();
    for (int s = tid; s < TSLOT; s += blockDim.x) atomicAdd(&cnt[ridx[s] & 7], 1);
    __syncthreads();
    if (tid == 0) {
        int a = 0;
        for (int e = 0; e < NE; ++e) { seg[e] = a; cur[e] = a; a += cnt[e]; }
        seg[NE] = a;
        int nt = 0;
        for (int e = 0; e < NE; ++e)
            for (int m0 = 0; m0 < cnt[e]; m0 += 64) d64[nt++] = (e << 16) | (m0 / 64);
        for (; nt < MAXT64; ++nt) d64[nt] = -1;
        nt = 0;
        for (int e = 0; e < NE; ++e)
            for (int m0 = 0; m0 < cnt[e]; m0 += 128) d128[nt++] = (e << 16) | (m0 / 128);
        for (; nt < MAXT128; ++nt) d128[nt] = -1;
    }
    __syncthreads();
    for (int s = tid; s < TSLOT; s += blockDim.x) {
        int e = ridx[s] & 7;
        int p = atomicAdd(&cur[e], 1);
        slot_of[p] = s;
        pos_of[s] = p;
    }
}

// ---------------- gather x rows into expert-sorted bf16 A ----------------
__global__ __launch_bounds__(256) void k_gather(const float* __restrict__ x,
                                                const int* __restrict__ slot_of,
                                                u16* __restrict__ A) {
    int r = blockIdx.x;
    int token = slot_of[r] >> 1;
    float4 v = ((const float4*)(x + (size_t)token * NH))[threadIdx.x];
    ushort4 o;
    o.x = f2bf(v.x); o.y = f2bf(v.y); o.z = f2bf(v.z); o.w = f2bf(v.w);
    ((ushort4*)(A + (size_t)r * NH))[threadIdx.x] = o;
}

// ---------------- transpose+convert: W[e][K][N] fp32 -> WT[e][N][K] bf16 ----------------
__global__ __launch_bounds__(256) void k_tr(const float* __restrict__ W,
                                            u16* __restrict__ WT, int K, int N) {
    __shared__ u16 T[64][66];
    int tid = threadIdx.x;
    const float* in = W + (size_t)blockIdx.z * K * N;
    u16* out = WT + (size_t)blockIdx.z * N * K;
    int n0 = blockIdx.x * 64, k0 = blockIdx.y * 64;
#pragma unroll
    for (int p = 0; p < 2; ++p) {
        int kr = p * 32 + (tid >> 4) * 2;      // even k row
        int nc = (tid & 15) * 4;
        const float* r0 = in + (size_t)(k0 + kr) * N + n0 + nc;
        float4 v0 = *(const float4*)r0;
        float4 v1 = *(const float4*)(r0 + N);
#pragma unroll
        for (int i = 0; i < 4; ++i) {
            unsigned lo = f2bf(((const float*)&v0)[i]);
            unsigned hi = f2bf(((const float*)&v1)[i]);
            *(unsigned*)&T[nc + i][kr] = lo | (hi << 16);
        }
    }
    __syncthreads();
#pragma unroll
    for (int p = 0; p < 2; ++p) {
        int idx = p * 256 + tid;
        int nr = idx >> 3, kc = (idx & 7) * 8;
        unsigned q0 = *(const unsigned*)&T[nr][kc + 0];
        unsigned q1 = *(const unsigned*)&T[nr][kc + 2];
        unsigned q2 = *(const unsigned*)&T[nr][kc + 4];
        unsigned q3 = *(const unsigned*)&T[nr][kc + 6];
        uint4 vv = {q0, q1, q2, q3};
        *(uint4*)(out + (size_t)(n0 + nr) * K + k0 + kc) = vv;
    }
}

// ---------------- fast gate_up: 128x64 tile, dbuf counted-vmcnt pipeline ----------------
__global__ __launch_bounds__(256) void k_gateup_f(
        const u16* __restrict__ A,       // [TSLOT][NH] bf16, expert-sorted
        const u16* __restrict__ wt,      // [NE][NGU][NH] bf16 (n-major)
        const float* __restrict__ bias,  // [NE][NGU]
        const int* __restrict__ seg, const int* __restrict__ desc,
        u16* __restrict__ inter) {       // [TSLOT][NI] bf16
    int d = desc[blockIdx.x];
    if (d < 0) return;
    int e = d >> 16, mt = d & 0xffff;
    int seg0 = seg[e], Te = seg[e + 1] - seg0, m0 = mt * 128;

    __shared__ __align__(16) u16 As0[128 * 64];
    __shared__ __align__(16) u16 As1[128 * 64];
    __shared__ __align__(16) u16 Bs0[64 * 64];
    __shared__ __align__(16) u16 Bs1[64 * 64];

    int tid = threadIdx.x;
    int lane = tid & 63, w = tid >> 6;
    int ml = lane & 15, kq = lane >> 4;
    int wm = w >> 1, wn = w & 1;
    int n0 = blockIdx.y * 64;
    const u16* wte = wt + (size_t)e * NGU * NH;
    int dr = lane >> 3, db = (lane & 7) ^ dr;

    const u16* aptr[4];
#pragma unroll
    for (int c = 0; c < 4; ++c) {
        int gr = seg0 + m0 + c * 32 + w * 8 + dr;
        if (gr > TSLOT - 1) gr = TSLOT - 1;              // clamp (pad-free ws)
        aptr[c] = A + (size_t)gr * NH + db * 8;
    }
    const u16* bptr[2];
#pragma unroll
    for (int c = 0; c < 2; ++c)
        bptr[c] = wte + (size_t)(n0 + c * 32 + w * 8 + dr) * NH + db * 8;

    auto stage = [&](u16* AS, u16* BS, int kb) {
#pragma unroll
        for (int c = 0; c < 4; ++c) lds_dma16(aptr[c] + kb, AS + c * 2048 + w * 512);
#pragma unroll
        for (int c = 0; c < 2; ++c) lds_dma16(bptr[c] + kb, BS + c * 2048 + w * 512);
    };

    f32x4 zero = {0.f, 0.f, 0.f, 0.f};
    f32x4 acc[4][2];
#pragma unroll
    for (int i = 0; i < 4; ++i) { acc[i][0] = zero; acc[i][1] = zero; }

    auto compute = [&](const u16* AS, const u16* BS) {
#pragma unroll
        for (int kk = 0; kk < 64; kk += 32) {
            s16x8 af[4], bf[2];
#pragma unroll
            for (int i = 0; i < 4; ++i)
                af[i] = *(const s16x8*)((const char*)AS + lds_off(wm * 64 + i * 16 + ml, (kk >> 3) + kq));
#pragma unroll
            for (int i = 0; i < 2; ++i)
                bf[i] = *(const s16x8*)((const char*)BS + lds_off(wn * 32 + i * 16 + ml, (kk >> 3) + kq));
#pragma unroll
            for (int mi = 0; mi < 4; ++mi)
#pragma unroll
                for (int ni = 0; ni < 2; ++ni)
                    acc[mi][ni] = __builtin_amdgcn_mfma_f32_16x16x32_bf16(
                        af[mi], bf[ni], acc[mi][ni], 0, 0, 0);
        }
    };

    stage(As0, Bs0, 0);
    for (int t = 0; t < 16; t += 2) {
        stage(As1, Bs1, (t + 1) << 6);
        WAIT_VM6;                               // buf0's 6 loads done, buf1's in flight
        __builtin_amdgcn_s_barrier();
        PIPE_FENCE;
        __builtin_amdgcn_s_setprio(1);
        compute(As0, Bs0);
        __builtin_amdgcn_s_setprio(0);
        PIPE_FENCE;
        __builtin_amdgcn_s_barrier();           // all reads of buf0 issued before overwrite
        if (t < 14) {
            stage(As0, Bs0, (t + 2) << 6);
            WAIT_VM6;
        } else {
            WAIT_VM0;
        }
        __builtin_amdgcn_s_barrier();
        PIPE_FENCE;
        __builtin_amdgcn_s_setprio(1);
        compute(As1, Bs1);
        __builtin_amdgcn_s_setprio(0);
        PIPE_FENCE;
        __builtin_amdgcn_s_barrier();
    }

#pragma unroll
    for (int ni = 0; ni < 2; ++ni) {
        int n = n0 + wn * 32 + ni * 16 + ml;
        float bv = bias[e * NGU + n];
#pragma unroll
        for (int mi = 0; mi < 4; ++mi) {
#pragma unroll
            for (int r = 0; r < 4; ++r) {
                float v = acc[mi][ni][r] + bv;
                float pr = __shfl_xor(v, 1, 64);
                float g = (lane & 1) ? pr : v;
                float u = (lane & 1) ? v : pr;
                g = fminf(g, 7.0f);
                u = fminf(fmaxf(u, -7.0f), 7.0f);
                float glu = g / (1.0f + __expf(-1.702f * g));
                float y = (u + 1.0f) * glu;
                int mloc = wm * 64 + mi * 16 + kq * 4 + r;
                if (!(lane & 1) && (m0 + mloc) < Te)
                    inter[(size_t)(seg0 + m0 + mloc) * NI + (n >> 1)] = f2bf(y);
            }
        }
    }
}

// ---------------- fast down: 128x64 tile, splitKx2, dbuf pipeline, fused atomic scatter ----
__global__ __launch_bounds__(256) void k_down_f(
        const u16* __restrict__ inter,   // [TSLOT][NI] bf16
        const u16* __restrict__ wt,      // [NE][NH][NI] bf16 (n-major)
        const float* __restrict__ bias,  // [NE][NH]
        const float* __restrict__ rw,    // [MTOK][NE]
        const int* __restrict__ seg, const int* __restrict__ desc,
        const int* __restrict__ slot_of,
        float* __restrict__ out) {       // [MTOK][NH] fp32 (pre-zeroed)
    int d = desc[blockIdx.x];
    if (d < 0) return;
    int e = d >> 16, mt = d & 0xffff;
    int seg0 = seg[e], Te = seg[e + 1] - seg0, m0 = mt * 128;
    int kz = blockIdx.z;

    __shared__ __align__(16) u16 As0[128 * 64];
    __shared__ __align__(16) u16 As1[128 * 64];
    __shared__ __align__(16) u16 Bs0[64 * 64];
    __shared__ __align__(16) u16 Bs1[64 * 64];
    __shared__ int tokS[128];
    __shared__ float wgtS[128];

    int tid = threadIdx.x;
    if (tid < 128) {
        int m = m0 + tid;
        if (m < Te) {
            int token = slot_of[seg0 + m] >> 1;
            tokS[tid] = token;
            wgtS[tid] = rw[token * NE + e];
        } else {
            tokS[tid] = 0;
            wgtS[tid] = 0.0f;
        }
    }

    int lane = tid & 63, w = tid >> 6;
    int ml = lane & 15, kq = lane >> 4;
    int wm = w >> 1, wn = w & 1;
    int n0 = blockIdx.y * 64;
    const u16* wte = wt + (size_t)e * NH * NI;
    int dr = lane >> 3, db = (lane & 7) ^ dr;
    int kbeg = kz * (NI / 2);

    const u16* aptr[4];
#pragma unroll
    for (int c = 0; c < 4; ++c) {
        int gr = seg0 + m0 + c * 32 + w * 8 + dr;
        if (gr > TSLOT - 1) gr = TSLOT - 1;              // clamp (pad-free ws)
        aptr[c] = inter + (size_t)gr * NI + db * 8;
    }
    const u16* bptr[2];
#pragma unroll
    for (int c = 0; c < 2; ++c)
        bptr[c] = wte + (size_t)(n0 + c * 32 + w * 8 + dr) * NI + db * 8;

    auto stage = [&](u16* AS, u16* BS, int kb) {
#pragma unroll
        for (int c = 0; c < 4; ++c) lds_dma16(aptr[c] + kb, AS + c * 2048 + w * 512);
#pragma unroll
        for (int c = 0; c < 2; ++c) lds_dma16(bptr[c] + kb, BS + c * 2048 + w * 512);
    };

    f32x4 zero = {0.f, 0.f, 0.f, 0.f};
    f32x4 acc[4][2];
#pragma unroll
    for (int i = 0; i < 4; ++i) { acc[i][0] = zero; acc[i][1] = zero; }

    auto compute = [&](const u16* AS, const u16* BS) {
#pragma unroll
        for (int kk = 0; kk < 64; kk += 32) {
            s16x8 af[4], bf[2];
#pragma unroll
            for (int i = 0; i < 4; ++i)
                af[i] = *(const s16x8*)((const char*)AS + lds_off(wm * 64 + i * 16 + ml, (kk >> 3) + kq));
#pragma unroll
            for (int i = 0; i < 2; ++i)
                bf[i] = *(const s16x8*)((const char*)BS + lds_off(wn * 32 + i * 16 + ml, (kk >> 3) + kq));
#pragma unroll
            for (int mi = 0; mi < 4; ++mi)
#pragma unroll
                for (int ni = 0; ni < 2; ++ni)
                    acc[mi][ni] = __builtin_amdgcn_mfma_f32_16x16x32_bf16(
                        af[mi], bf[ni], acc[mi][ni], 0, 0, 0);
        }
    };

    stage(As0, Bs0, kbeg);
    for (int t = 0; t < 8; t += 2) {
        stage(As1, Bs1, kbeg + ((t + 1) << 6));
        WAIT_VM6;
        __builtin_amdgcn_s_barrier();
        PIPE_FENCE;
        __builtin_amdgcn_s_setprio(1);
        compute(As0, Bs0);
        __builtin_amdgcn_s_setprio(0);
        PIPE_FENCE;
        __builtin_amdgcn_s_barrier();
        if (t < 6) {
            stage(As0, Bs0, kbeg + ((t + 2) << 6));
            WAIT_VM6;
        } else {
            WAIT_VM0;
        }
        __builtin_amdgcn_s_barrier();
        PIPE_FENCE;
        __builtin_amdgcn_s_setprio(1);
        compute(As1, Bs1);
        __builtin_amdgcn_s_setprio(0);
        PIPE_FENCE;
        __builtin_amdgcn_s_barrier();
    }

    float bv[2];
#pragma unroll
    for (int ni = 0; ni < 2; ++ni)
        bv[ni] = kz ? 0.0f : bias[e * NH + n0 + wn * 32 + ni * 16 + ml];

#pragma unroll
    for (int mi = 0; mi < 4; ++mi) {
#pragma unroll
        for (int r = 0; r < 4; ++r) {
            int mloc = wm * 64 + mi * 16 + kq * 4 + r;
            if ((m0 + mloc) < Te) {
                int token = tokS[mloc];
                float wgt = wgtS[mloc];
#pragma unroll
                for (int ni = 0; ni < 2; ++ni) {
                    int n = n0 + wn * 32 + ni * 16 + ml;
                    atomicAdd(&out[(size_t)token * NH + n], (acc[mi][ni][r] + bv[ni]) * wgt);
                }
            }
        }
    }
}

// ---------------- slow-path kernels (round-2, proven) ----------------
__global__ __launch_bounds__(256) void k_gateup_s(
        const float* __restrict__ x, const float* __restrict__ w,
        const float* __restrict__ bias,
        const int* __restrict__ seg, const int* __restrict__ desc,
        const int* __restrict__ slot_of, u16* __restrict__ inter) {
    int d = desc[blockIdx.x];
    if (d < 0) return;
    int e = d >> 16, mt = d & 0xffff;
    int seg0 = seg[e], Te = seg[e + 1] - seg0, m0 = mt * 64;
    __shared__ u16 As[64 * 40];
    __shared__ int tok[64];
    int tid = threadIdx.x;
    if (tid < 64) {
        int m = m0 + tid;
        tok[tid] = (m < Te) ? (slot_of[seg0 + m] >> 1) : -1;
    }
    __syncthreads();
    int lane = tid & 63, wave = tid >> 6;
    int arow = tid >> 2, acol = (tid & 3) * 8;
    int ta = tok[arow];
    int kq = lane >> 4, ml = lane & 15;
    int nb = blockIdx.y * 128 + wave * 32;
    const float* wp = w + (size_t)e * NH * NGU;
    f32x4 zero = {0.f, 0.f, 0.f, 0.f};
    f32x4 acc[4][2];
#pragma unroll
    for (int i = 0; i < 4; ++i) { acc[i][0] = zero; acc[i][1] = zero; }
    for (int kb = 0; kb < NH; kb += 32) {
        float4 a0 = {0, 0, 0, 0}, a1 = {0, 0, 0, 0};
        if (ta >= 0) {
            const float* xp = x + (size_t)ta * NH + kb + acol;
            a0 = *(const float4*)xp; a1 = *(const float4*)(xp + 4);
        }
        s16x8 av;
        av[0] = (short)f2bf(a0.x); av[1] = (short)f2bf(a0.y);
        av[2] = (short)f2bf(a0.z); av[3] = (short)f2bf(a0.w);
        av[4] = (short)f2bf(a1.x); av[5] = (short)f2bf(a1.y);
        av[6] = (short)f2bf(a1.z); av[7] = (short)f2bf(a1.w);
        __syncthreads();
        *(s16x8*)&As[arow * 40 + acol] = av;
        __syncthreads();
        s16x8 afr[4];
#pragma unroll
        for (int msi = 0; msi < 4; ++msi)
            afr[msi] = *(const s16x8*)&As[(msi * 16 + ml) * 40 + kq * 8];
        s16x8 bfr[2];
#pragma unroll
        for (int s = 0; s < 2; ++s) {
            const float* bp = wp + (size_t)(kb + kq * 8) * NGU + nb + s * 16 + ml;
#pragma unroll
            for (int j = 0; j < 8; ++j) bfr[s][j] = (short)f2bf(bp[(size_t)j * NGU]);
        }
#pragma unroll
        for (int msi = 0; msi < 4; ++msi)
#pragma unroll
            for (int s = 0; s < 2; ++s)
                acc[msi][s] = __builtin_amdgcn_mfma_f32_16x16x32_bf16(
                    afr[msi], bfr[s], acc[msi][s], 0, 0, 0);
    }
#pragma unroll
    for (int s = 0; s < 2; ++s) {
        int n = nb + s * 16 + ml;
        float bv = bias[e * NGU + n];
#pragma unroll
        for (int msi = 0; msi < 4; ++msi) {
#pragma unroll
            for (int r = 0; r < 4; ++r) {
                float v = acc[msi][s][r] + bv;
                float pr = __shfl_xor(v, 1, 64);
                float g = (lane & 1) ? pr : v;
                float u = (lane & 1) ? v : pr;
                g = fminf(g, 7.0f);
                u = fminf(fmaxf(u, -7.0f), 7.0f);
                float glu = g / (1.0f + __expf(-1.702f * g));
                float y = (u + 1.0f) * glu;
                int mrow = m0 + msi * 16 + kq * 4 + r;
                if (!(lane & 1) && mrow < Te)
                    inter[(size_t)(seg0 + mrow) * NI + (n >> 1)] = f2bf(y);
            }
        }
    }
}

__global__ __launch_bounds__(256) void k_down_s(
        const u16* __restrict__ inter, const float* __restrict__ w,
        const float* __restrict__ bias, const float* __restrict__ rw,
        const int* __restrict__ seg, const int* __restrict__ desc,
        const int* __restrict__ slot_of, float* __restrict__ out) {
    int d = desc[blockIdx.x];
    if (d < 0) return;
    int e = d >> 16, mt = d & 0xffff;
    int seg0 = seg[e], Te = seg[e + 1] - seg0, m0 = mt * 64;
    __shared__ u16 As[64 * 40];
    int tid = threadIdx.x;
    int lane = tid & 63, wave = tid >> 6;
    int arow = tid >> 2, acol = (tid & 3) * 8;
    bool avalid = (m0 + arow) < Te;
    int kq = lane >> 4, ml = lane & 15;
    int nb = blockIdx.y * 128 + wave * 32;
    const float* wp = w + (size_t)e * NI * NH;
    f32x4 zero = {0.f, 0.f, 0.f, 0.f};
    f32x4 acc[4][2];
#pragma unroll
    for (int i = 0; i < 4; ++i) { acc[i][0] = zero; acc[i][1] = zero; }
    for (int kb = 0; kb < NI; kb += 32) {
        s16x8 av = {0, 0, 0, 0, 0, 0, 0, 0};
        if (avalid) av = *(const s16x8*)(inter + (size_t)(seg0 + m0 + arow) * NI + kb + acol);
        __syncthreads();
        *(s16x8*)&As[arow * 40 + acol] = av;
        __syncthreads();
        s16x8 afr[4];
#pragma unroll
        for (int msi = 0; msi < 4; ++msi)
            afr[msi] = *(const s16x8*)&As[(msi * 16 + ml) * 40 + kq * 8];
        s16x8 bfr[2];
#pragma unroll
        for (int s = 0; s < 2; ++s) {
            const float* bp = wp + (size_t)(kb + kq * 8) * NH + nb + s * 16 + ml;
#pragma unroll
            for (int j = 0; j < 8; ++j) bfr[s][j] = (short)f2bf(bp[(size_t)j * NH]);
        }
#pragma unroll
        for (int msi = 0; msi < 4; ++msi)
#pragma unroll
            for (int s = 0; s < 2; ++s)
                acc[msi][s] = __builtin_amdgcn_mfma_f32_16x16x32_bf16(
                    afr[msi], bfr[s], acc[msi][s], 0, 0, 0);
    }
    float bv[2];
    bv[0] = bias[e * NH + nb + ml];
    bv[1] = bias[e * NH + nb + 16 + ml];
#pragma unroll
    for (int msi = 0; msi < 4; ++msi) {
#pragma unroll
        for (int r = 0; r < 4; ++r) {
            int mrow = m0 + msi * 16 + kq * 4 + r;
            if (mrow < Te) {
                int slot = slot_of[seg0 + mrow];
                int token = slot >> 1;
                float wgt = rw[token * NE + e];
#pragma unroll
                for (int s = 0; s < 2; ++s) {
                    int n = nb + s * 16 + ml;
                    atomicAdd(&out[(size_t)token * NH + n], (acc[msi][s][r] + bv[s]) * wgt);
                }
            }
        }
    }
}

extern "C" void kernel_launch(void* const* d_in, const int* in_sizes, int n_in,
                              void* d_out, int out_size, void* d_ws, size_t ws_size,
                              hipStream_t stream) {
    const float* x   = (const float*)d_in[0];
    const int*   ri  = (const int*)d_in[1];
    const float* rw  = (const float*)d_in[2];
    const float* wgu = (const float*)d_in[3];
    const float* bgu = (const float*)d_in[4];
    const float* wd  = (const float*)d_in[5];
    const float* bd  = (const float*)d_in[6];
    float* out = (float*)d_out;

    char* ws = (char*)d_ws;
    int* seg     = (int*)(ws + WS_SEG);
    int* d64     = (int*)(ws + WS_DESC64);
    int* d128    = (int*)(ws + WS_DESC128);
    int* slot_of = (int*)(ws + WS_SLOT);
    int* pos_of  = (int*)(ws + WS_POS);
    u16* inter   = (u16*)(ws + WS_INTER);

    hipLaunchKernelGGL(k_build, dim3(1), dim3(256), 0, stream, ri, seg, d64, d128,
                       slot_of, pos_of);
    hipMemsetAsync(out, 0, (size_t)MTOK * NH * sizeof(float), stream);

    if (ws_size >= WS_NEED_FAST) {
        u16* aReg = (u16*)(ws + WS_AREG);
        u16* wReg = (u16*)(ws + WS_WREG);
        hipLaunchKernelGGL(k_tr, dim3(NGU / 64, NH / 64, NE), dim3(256), 0, stream,
                           wgu, wReg, NH, NGU);
        hipLaunchKernelGGL(k_gather, dim3(TSLOT), dim3(256), 0, stream, x, slot_of, aReg);
        hipLaunchKernelGGL(k_gateup_f, dim3(MAXT128, NGU / 64), dim3(256), 0, stream,
                           aReg, wReg, bgu, seg, d128, inter);
        hipLaunchKernelGGL(k_tr, dim3(NH / 64, NI / 64, NE), dim3(256), 0, stream,
                           wd, wReg, NI, NH);
        hipLaunchKernelGGL(k_down_f, dim3(MAXT128, NH / 64, 2), dim3(256), 0, stream,
                           inter, wReg, bd, rw, seg, d128, slot_of, out);
    } else {
        hipLaunchKernelGGL(k_gateup_s, dim3(MAXT64, NGU / 128), dim3(256), 0, stream,
                           x, wgu, bgu, seg, d64, slot_of, inter);
        hipLaunchKernelGGL(k_down_s, dim3(MAXT64, NH / 128), dim3(256), 0, stream,
                           inter, wd, bd, rw, seg, d64, slot_of, out);
    }
}

// Round 5
// 221.953 us; speedup vs baseline: 1.2152x; 1.1189x over previous
//
#include <hip/hip_runtime.h>

#define NE 8
#define NH 1024
#define NI 1024
#define NGU 2048
#define MTOK 2048
#define TSLOT 4096

#define MAXT64 80     // slow path: 64-row tiles
#define MAXT128 40    // fast path: 128-row tiles

typedef short s16x8 __attribute__((ext_vector_type(8)));
typedef float f32x4 __attribute__((ext_vector_type(4)));
typedef unsigned short u16;

// ---- ws layout (bytes) ----
#define WS_SEG      0
#define WS_DESC64   64
#define WS_DESC128  384
#define WS_SLOT     1024          // 4096 ints -> 17408
#define WS_POS      17408         // 4096 ints -> 33792
#define WS_INTER    33792         // bf16 [4096][1024] -> +8388608 = 8422400
#define WS_AREG     8422400UL     // A bf16 [2048][1024] unsorted (4.19MB) -> 12616704
#define WS_WREG     12616704UL    // WT_gu bf16 33.55MB -> 46171136
#define WS_WTD      46171136UL    // WT_d bf16 16.78MB -> 62948352 (piggyback path only)
#define WS_NEED_FAST  46171136UL
#define WS_NEED_PIGGY 62948352UL

__device__ inline u16 f2bf(float f) {
    unsigned u = __builtin_bit_cast(unsigned, f);
    u += 0x7fffu + ((u >> 16) & 1u);
    return (u16)(u >> 16);
}

__device__ inline void lds_dma16(const u16* g, u16* l) {
    __builtin_amdgcn_global_load_lds(
        (const __attribute__((address_space(1))) unsigned int*)g,
        (__attribute__((address_space(3))) unsigned int*)l, 16, 0, 0);
}

// swizzled LDS byte offset: row-stride 128B (64 bf16), 16B chunks XORed by row&7
__device__ inline int lds_off(int row, int blk) {
    return (row << 7) | (((blk ^ (row & 7)) & 7) << 4);
}

#define PIPE_FENCE asm volatile("" ::: "memory")
#define WAIT_VM6   asm volatile("s_waitcnt vmcnt(6)" ::: "memory")
#define WAIT_VM0   asm volatile("s_waitcnt vmcnt(0)" ::: "memory")

// ---- shared transpose tile: W[K][N] fp32 (one 64x64 tile) -> WT[N][K] bf16 ----
__device__ inline void tr_tile(const float* __restrict__ in, u16* __restrict__ outw,
                               int K, int N, int n0, int k0, int tid, u16 (*T)[66]) {
#pragma unroll
    for (int p = 0; p < 2; ++p) {
        int kr = p * 32 + (tid >> 4) * 2;      // even k row
        int nc = (tid & 15) * 4;
        const float* r0 = in + (size_t)(k0 + kr) * N + n0 + nc;
        float4 v0 = *(const float4*)r0;
        float4 v1 = *(const float4*)(r0 + N);
#pragma unroll
        for (int i = 0; i < 4; ++i) {
            unsigned lo = f2bf(((const float*)&v0)[i]);
            unsigned hi = f2bf(((const float*)&v1)[i]);
            *(unsigned*)&T[nc + i][kr] = lo | (hi << 16);
        }
    }
    __syncthreads();
#pragma unroll
    for (int p = 0; p < 2; ++p) {
        int idx = p * 256 + tid;
        int nr = idx >> 3, kc = (idx & 7) * 8;
        unsigned q0 = *(const unsigned*)&T[nr][kc + 0];
        unsigned q1 = *(const unsigned*)&T[nr][kc + 2];
        unsigned q2 = *(const unsigned*)&T[nr][kc + 4];
        unsigned q3 = *(const unsigned*)&T[nr][kc + 6];
        uint4 vv = {q0, q1, q2, q3};
        *(uint4*)(outw + (size_t)(n0 + nr) * K + k0 + kc) = vv;
    }
}

// ---------------- standalone transpose (4-launch fallback path) ----------------
__global__ __launch_bounds__(256) void k_tr(const float* __restrict__ W,
                                            u16* __restrict__ WT, int K, int N) {
    __shared__ u16 T[64][66];
    tr_tile(W + (size_t)blockIdx.z * K * N, WT + (size_t)blockIdx.z * N * K,
            K, N, blockIdx.x * 64, blockIdx.y * 64, threadIdx.x, T);
}

// ---------------- fused prep: build(1) + convert/zero(2048) + tr_gu(4096) ----------------
__global__ __launch_bounds__(256) void k_prep(
        const float* __restrict__ x, const int* __restrict__ ridx,
        const float* __restrict__ wgu,
        int* __restrict__ seg, int* __restrict__ d64, int* __restrict__ d128,
        int* __restrict__ slot_of, int* __restrict__ pos_of,
        u16* __restrict__ A, u16* __restrict__ wt_gu, float* __restrict__ out) {
    __shared__ int cnt[NE];
    __shared__ int cur[NE];
    __shared__ u16 T[64][66];
    int b = blockIdx.x;
    int tid = threadIdx.x;

    if (b == 0) {
        if (tid < NE) cnt[tid] = 0;
        __syncthreads();
        for (int s = tid; s < TSLOT; s += blockDim.x) atomicAdd(&cnt[ridx[s] & 7], 1);
        __syncthreads();
        if (tid == 0) {
            int a = 0;
            for (int e = 0; e < NE; ++e) { seg[e] = a; cur[e] = a; a += cnt[e]; }
            seg[NE] = a;
            int nt = 0;
            for (int e = 0; e < NE; ++e)
                for (int m0 = 0; m0 < cnt[e]; m0 += 64) d64[nt++] = (e << 16) | (m0 / 64);
            for (; nt < MAXT64; ++nt) d64[nt] = -1;
            nt = 0;
            for (int e = 0; e < NE; ++e)
                for (int m0 = 0; m0 < cnt[e]; m0 += 128) d128[nt++] = (e << 16) | (m0 / 128);
            for (; nt < MAXT128; ++nt) d128[nt] = -1;
        }
        __syncthreads();
        for (int s = tid; s < TSLOT; s += blockDim.x) {
            int e = ridx[s] & 7;
            int p = atomicAdd(&cur[e], 1);
            slot_of[p] = s;
            pos_of[s] = p;
        }
    } else if (b <= MTOK) {
        int t = b - 1;
        float4 v = ((const float4*)(x + (size_t)t * NH))[tid];
        ushort4 o;
        o.x = f2bf(v.x); o.y = f2bf(v.y); o.z = f2bf(v.z); o.w = f2bf(v.w);
        ((ushort4*)(A + (size_t)t * NH))[tid] = o;
        float4 z = {0.f, 0.f, 0.f, 0.f};
        ((float4*)(out + (size_t)t * NH))[tid] = z;
    } else {
        int id = b - (MTOK + 1);                 // 0..4095
        int e = id >> 9, rem = id & 511;
        int kblk = rem >> 5, nblk = rem & 31;    // K=NH: 16 kblks, N=NGU: 32 nblks
        tr_tile(wgu + (size_t)e * NH * NGU, wt_gu + (size_t)e * NGU * NH,
                NH, NGU, nblk * 64, kblk * 64, tid, T);
    }
}

// ---------------- fast gate_up: 128x64 tile, dbuf pipeline (+opt. piggybacked tr_d) ----------------
// piggyback blocks (x >= MAXT128) write wtd, which MUST be disjoint from wt.
__global__ __launch_bounds__(256) void k_gateup_f(
        const u16* __restrict__ A,       // [MTOK][NH] bf16, UNSORTED (token order)
        const u16* __restrict__ wt,      // [NE][NGU][NH] bf16 (n-major)
        const float* __restrict__ bias,  // [NE][NGU]
        const int* __restrict__ seg, const int* __restrict__ desc,
        const int* __restrict__ slot_of,
        u16* __restrict__ inter,         // [TSLOT][NI] bf16 (expert-sorted)
        const float* __restrict__ wd,    // [NE][NI][NH] fp32 (tr_d source)
        u16* __restrict__ wtd) {         // [NE][NH][NI] bf16 (tr_d dest, DISJOINT from wt)
    __shared__ __align__(16) char SM[49152];
    int tid = threadIdx.x;

    if (blockIdx.x >= MAXT128) {
        // piggyback: down-weight transpose (2048 blocks; output consumed by k_down_f)
        int id = (blockIdx.x - MAXT128) * 32 + blockIdx.y;   // 0..2047
        int e = id >> 8, rem = id & 255;
        int kblk = rem >> 4, nblk = rem & 15;                // K=NI:16, N=NH:16
        u16 (*T)[66] = (u16(*)[66])SM;
        tr_tile(wd + (size_t)e * NI * NH, wtd + (size_t)e * NH * NI,
                NI, NH, nblk * 64, kblk * 64, tid, T);
        return;
    }

    int d = desc[blockIdx.x];
    if (d < 0) return;
    int e = d >> 16, mt = d & 0xffff;
    int seg0 = seg[e], Te = seg[e + 1] - seg0, m0 = mt * 128;

    u16* As0 = (u16*)SM;                  // 16KB
    u16* As1 = (u16*)(SM + 16384);
    u16* Bs0 = (u16*)(SM + 32768);        // 8KB
    u16* Bs1 = (u16*)(SM + 40960);

    int lane = tid & 63, w = tid >> 6;
    int ml = lane & 15, kq = lane >> 4;
    int wm = w >> 1, wn = w & 1;
    int n0 = blockIdx.y * 64;
    const u16* wte = wt + (size_t)e * NGU * NH;
    int dr = lane >> 3, db = (lane & 7) ^ dr;

    const u16* aptr[4];
#pragma unroll
    for (int c = 0; c < 4; ++c) {
        int gr = seg0 + m0 + c * 32 + w * 8 + dr;
        if (gr > TSLOT - 1) gr = TSLOT - 1;              // clamp
        int tok = slot_of[gr] >> 1;                      // gather through sort map
        aptr[c] = A + (size_t)tok * NH + db * 8;
    }
    const u16* bptr[2];
#pragma unroll
    for (int c = 0; c < 2; ++c)
        bptr[c] = wte + (size_t)(n0 + c * 32 + w * 8 + dr) * NH + db * 8;

    auto stage = [&](u16* AS, u16* BS, int kb) {
#pragma unroll
        for (int c = 0; c < 4; ++c) lds_dma16(aptr[c] + kb, AS + c * 2048 + w * 512);
#pragma unroll
        for (int c = 0; c < 2; ++c) lds_dma16(bptr[c] + kb, BS + c * 2048 + w * 512);
    };

    f32x4 zero = {0.f, 0.f, 0.f, 0.f};
    f32x4 acc[4][2];
#pragma unroll
    for (int i = 0; i < 4; ++i) { acc[i][0] = zero; acc[i][1] = zero; }

    auto compute = [&](const u16* AS, const u16* BS) {
#pragma unroll
        for (int kk = 0; kk < 64; kk += 32) {
            s16x8 af[4], bf[2];
#pragma unroll
            for (int i = 0; i < 4; ++i)
                af[i] = *(const s16x8*)((const char*)AS + lds_off(wm * 64 + i * 16 + ml, (kk >> 3) + kq));
#pragma unroll
            for (int i = 0; i < 2; ++i)
                bf[i] = *(const s16x8*)((const char*)BS + lds_off(wn * 32 + i * 16 + ml, (kk >> 3) + kq));
#pragma unroll
            for (int mi = 0; mi < 4; ++mi)
#pragma unroll
                for (int ni = 0; ni < 2; ++ni)
                    acc[mi][ni] = __builtin_amdgcn_mfma_f32_16x16x32_bf16(
                        af[mi], bf[ni], acc[mi][ni], 0, 0, 0);
        }
    };

    stage(As0, Bs0, 0);
    for (int t = 0; t < 16; t += 2) {
        stage(As1, Bs1, (t + 1) << 6);
        WAIT_VM6;
        __builtin_amdgcn_s_barrier();
        PIPE_FENCE;
        __builtin_amdgcn_s_setprio(1);
        compute(As0, Bs0);
        __builtin_amdgcn_s_setprio(0);
        PIPE_FENCE;
        __builtin_amdgcn_s_barrier();
        if (t < 14) {
            stage(As0, Bs0, (t + 2) << 6);
            WAIT_VM6;
        } else {
            WAIT_VM0;
        }
        __builtin_amdgcn_s_barrier();
        PIPE_FENCE;
        __builtin_amdgcn_s_setprio(1);
        compute(As1, Bs1);
        __builtin_amdgcn_s_setprio(0);
        PIPE_FENCE;
        __builtin_amdgcn_s_barrier();
    }

#pragma unroll
    for (int ni = 0; ni < 2; ++ni) {
        int n = n0 + wn * 32 + ni * 16 + ml;
        float bv = bias[e * NGU + n];
#pragma unroll
        for (int mi = 0; mi < 4; ++mi) {
#pragma unroll
            for (int r = 0; r < 4; ++r) {
                float v = acc[mi][ni][r] + bv;
                float pr = __shfl_xor(v, 1, 64);
                float g = (lane & 1) ? pr : v;
                float u = (lane & 1) ? v : pr;
                g = fminf(g, 7.0f);
                u = fminf(fmaxf(u, -7.0f), 7.0f);
                float glu = g / (1.0f + __expf(-1.702f * g));
                float y = (u + 1.0f) * glu;
                int mloc = wm * 64 + mi * 16 + kq * 4 + r;
                if (!(lane & 1) && (m0 + mloc) < Te)
                    inter[(size_t)(seg0 + m0 + mloc) * NI + (n >> 1)] = f2bf(y);
            }
        }
    }
}

// ---------------- fast down: 128x64 tile, FULL K, dbuf pipeline, fused atomic scatter ----
__global__ __launch_bounds__(256) void k_down_f(
        const u16* __restrict__ inter,   // [TSLOT][NI] bf16
        const u16* __restrict__ wt,      // [NE][NH][NI] bf16 (n-major)
        const float* __restrict__ bias,  // [NE][NH]
        const float* __restrict__ rw,    // [MTOK][NE]
        const int* __restrict__ seg, const int* __restrict__ desc,
        const int* __restrict__ slot_of,
        float* __restrict__ out) {       // [MTOK][NH] fp32 (pre-zeroed)
    int d = desc[blockIdx.x];
    if (d < 0) return;
    int e = d >> 16, mt = d & 0xffff;
    int seg0 = seg[e], Te = seg[e + 1] - seg0, m0 = mt * 128;

    __shared__ __align__(16) u16 As0[128 * 64];
    __shared__ __align__(16) u16 As1[128 * 64];
    __shared__ __align__(16) u16 Bs0[64 * 64];
    __shared__ __align__(16) u16 Bs1[64 * 64];
    __shared__ int tokS[128];
    __shared__ float wgtS[128];

    int tid = threadIdx.x;
    if (tid < 128) {
        int m = m0 + tid;
        if (m < Te) {
            int token = slot_of[seg0 + m] >> 1;
            tokS[tid] = token;
            wgtS[tid] = rw[token * NE + e];
        } else {
            tokS[tid] = 0;
            wgtS[tid] = 0.0f;
        }
    }

    int lane = tid & 63, w = tid >> 6;
    int ml = lane & 15, kq = lane >> 4;
    int wm = w >> 1, wn = w & 1;
    int n0 = blockIdx.y * 64;
    const u16* wte = wt + (size_t)e * NH * NI;
    int dr = lane >> 3, db = (lane & 7) ^ dr;

    const u16* aptr[4];
#pragma unroll
    for (int c = 0; c < 4; ++c) {
        int gr = seg0 + m0 + c * 32 + w * 8 + dr;
        if (gr > TSLOT - 1) gr = TSLOT - 1;
        aptr[c] = inter + (size_t)gr * NI + db * 8;
    }
    const u16* bptr[2];
#pragma unroll
    for (int c = 0; c < 2; ++c)
        bptr[c] = wte + (size_t)(n0 + c * 32 + w * 8 + dr) * NI + db * 8;

    auto stage = [&](u16* AS, u16* BS, int kb) {
#pragma unroll
        for (int c = 0; c < 4; ++c) lds_dma16(aptr[c] + kb, AS + c * 2048 + w * 512);
#pragma unroll
        for (int c = 0; c < 2; ++c) lds_dma16(bptr[c] + kb, BS + c * 2048 + w * 512);
    };

    f32x4 zero = {0.f, 0.f, 0.f, 0.f};
    f32x4 acc[4][2];
#pragma unroll
    for (int i = 0; i < 4; ++i) { acc[i][0] = zero; acc[i][1] = zero; }

    auto compute = [&](const u16* AS, const u16* BS) {
#pragma unroll
        for (int kk = 0; kk < 64; kk += 32) {
            s16x8 af[4], bf[2];
#pragma unroll
            for (int i = 0; i < 4; ++i)
                af[i] = *(const s16x8*)((const char*)AS + lds_off(wm * 64 + i * 16 + ml, (kk >> 3) + kq));
#pragma unroll
            for (int i = 0; i < 2; ++i)
                bf[i] = *(const s16x8*)((const char*)BS + lds_off(wn * 32 + i * 16 + ml, (kk >> 3) + kq));
#pragma unroll
            for (int mi = 0; mi < 4; ++mi)
#pragma unroll
                for (int ni = 0; ni < 2; ++ni)
                    acc[mi][ni] = __builtin_amdgcn_mfma_f32_16x16x32_bf16(
                        af[mi], bf[ni], acc[mi][ni], 0, 0, 0);
        }
    };

    stage(As0, Bs0, 0);
    for (int t = 0; t < 16; t += 2) {
        stage(As1, Bs1, (t + 1) << 6);
        WAIT_VM6;
        __builtin_amdgcn_s_barrier();
        PIPE_FENCE;
        __builtin_amdgcn_s_setprio(1);
        compute(As0, Bs0);
        __builtin_amdgcn_s_setprio(0);
        PIPE_FENCE;
        __builtin_amdgcn_s_barrier();
        if (t < 14) {
            stage(As0, Bs0, (t + 2) << 6);
            WAIT_VM6;
        } else {
            WAIT_VM0;
        }
        __builtin_amdgcn_s_barrier();
        PIPE_FENCE;
        __builtin_amdgcn_s_setprio(1);
        compute(As1, Bs1);
        __builtin_amdgcn_s_setprio(0);
        PIPE_FENCE;
        __builtin_amdgcn_s_barrier();
    }

    float bv[2];
#pragma unroll
    for (int ni = 0; ni < 2; ++ni)
        bv[ni] = bias[e * NH + n0 + wn * 32 + ni * 16 + ml];

#pragma unroll
    for (int mi = 0; mi < 4; ++mi) {
#pragma unroll
        for (int r = 0; r < 4; ++r) {
            int mloc = wm * 64 + mi * 16 + kq * 4 + r;
            if ((m0 + mloc) < Te) {
                int token = tokS[mloc];
                float wgt = wgtS[mloc];
#pragma unroll
                for (int ni = 0; ni < 2; ++ni) {
                    int n = n0 + wn * 32 + ni * 16 + ml;
                    atomicAdd(&out[(size_t)token * NH + n], (acc[mi][ni][r] + bv[ni]) * wgt);
                }
            }
        }
    }
}

// ---------------- slow-path kernels (round-2, proven) ----------------
__global__ void k_build(const int* __restrict__ ridx, int* __restrict__ seg,
                        int* __restrict__ d64, int* __restrict__ d128,
                        int* __restrict__ slot_of, int* __restrict__ pos_of) {
    __shared__ int cnt[NE];
    __shared__ int cur[NE];
    int tid = threadIdx.x;
    if (tid < NE) cnt[tid] = 0;
    __syncthreads();
    for (int s = tid; s < TSLOT; s += blockDim.x) atomicAdd(&cnt[ridx[s] & 7], 1);
    __syncthreads();
    if (tid == 0) {
        int a = 0;
        for (int e = 0; e < NE; ++e) { seg[e] = a; cur[e] = a; a += cnt[e]; }
        seg[NE] = a;
        int nt = 0;
        for (int e = 0; e < NE; ++e)
            for (int m0 = 0; m0 < cnt[e]; m0 += 64) d64[nt++] = (e << 16) | (m0 / 64);
        for (; nt < MAXT64; ++nt) d64[nt] = -1;
        nt = 0;
        for (int e = 0; e < NE; ++e)
            for (int m0 = 0; m0 < cnt[e]; m0 += 128) d128[nt++] = (e << 16) | (m0 / 128);
        for (; nt < MAXT128; ++nt) d128[nt] = -1;
    }
    __syncthreads();
    for (int s = tid; s < TSLOT; s += blockDim.x) {
        int e = ridx[s] & 7;
        int p = atomicAdd(&cur[e], 1);
        slot_of[p] = s;
        pos_of[s] = p;
    }
}

__global__ __launch_bounds__(256) void k_gateup_s(
        const float* __restrict__ x, const float* __restrict__ w,
        const float* __restrict__ bias,
        const int* __restrict__ seg, const int* __restrict__ desc,
        const int* __restrict__ slot_of, u16* __restrict__ inter) {
    int d = desc[blockIdx.x];
    if (d < 0) return;
    int e = d >> 16, mt = d & 0xffff;
    int seg0 = seg[e], Te = seg[e + 1] - seg0, m0 = mt * 64;
    __shared__ u16 As[64 * 40];
    __shared__ int tok[64];
    int tid = threadIdx.x;
    if (tid < 64) {
        int m = m0 + tid;
        tok[tid] = (m < Te) ? (slot_of[seg0 + m] >> 1) : -1;
    }
    __syncthreads();
    int lane = tid & 63, wave = tid >> 6;
    int arow = tid >> 2, acol = (tid & 3) * 8;
    int ta = tok[arow];
    int kq = lane >> 4, ml = lane & 15;
    int nb = blockIdx.y * 128 + wave * 32;
    const float* wp = w + (size_t)e * NH * NGU;
    f32x4 zero = {0.f, 0.f, 0.f, 0.f};
    f32x4 acc[4][2];
#pragma unroll
    for (int i = 0; i < 4; ++i) { acc[i][0] = zero; acc[i][1] = zero; }
    for (int kb = 0; kb < NH; kb += 32) {
        float4 a0 = {0, 0, 0, 0}, a1 = {0, 0, 0, 0};
        if (ta >= 0) {
            const float* xp = x + (size_t)ta * NH + kb + acol;
            a0 = *(const float4*)xp; a1 = *(const float4*)(xp + 4);
        }
        s16x8 av;
        av[0] = (short)f2bf(a0.x); av[1] = (short)f2bf(a0.y);
        av[2] = (short)f2bf(a0.z); av[3] = (short)f2bf(a0.w);
        av[4] = (short)f2bf(a1.x); av[5] = (short)f2bf(a1.y);
        av[6] = (short)f2bf(a1.z); av[7] = (short)f2bf(a1.w);
        __syncthreads();
        *(s16x8*)&As[arow * 40 + acol] = av;
        __syncthreads();
        s16x8 afr[4];
#pragma unroll
        for (int msi = 0; msi < 4; ++msi)
            afr[msi] = *(const s16x8*)&As[(msi * 16 + ml) * 40 + kq * 8];
        s16x8 bfr[2];
#pragma unroll
        for (int s = 0; s < 2; ++s) {
            const float* bp = wp + (size_t)(kb + kq * 8) * NGU + nb + s * 16 + ml;
#pragma unroll
            for (int j = 0; j < 8; ++j) bfr[s][j] = (short)f2bf(bp[(size_t)j * NGU]);
        }
#pragma unroll
        for (int msi = 0; msi < 4; ++msi)
#pragma unroll
            for (int s = 0; s < 2; ++s)
                acc[msi][s] = __builtin_amdgcn_mfma_f32_16x16x32_bf16(
                    afr[msi], bfr[s], acc[msi][s], 0, 0, 0);
    }
#pragma unroll
    for (int s = 0; s < 2; ++s) {
        int n = nb + s * 16 + ml;
        float bv = bias[e * NGU + n];
#pragma unroll
        for (int msi = 0; msi < 4; ++msi) {
#pragma unroll
            for (int r = 0; r < 4; ++r) {
                float v = acc[msi][s][r] + bv;
                float pr = __shfl_xor(v, 1, 64);
                float g = (lane & 1) ? pr : v;
                float u = (lane & 1) ? v : pr;
                g = fminf(g, 7.0f);
                u = fminf(fmaxf(u, -7.0f), 7.0f);
                float glu = g / (1.0f + __expf(-1.702f * g));
                float y = (u + 1.0f) * glu;
                int mrow = m0 + msi * 16 + kq * 4 + r;
                if (!(lane & 1) && mrow < Te)
                    inter[(size_t)(seg0 + mrow) * NI + (n >> 1)] = f2bf(y);
            }
        }
    }
}

__global__ __launch_bounds__(256) void k_down_s(
        const u16* __restrict__ inter, const float* __restrict__ w,
        const float* __restrict__ bias, const float* __restrict__ rw,
        const int* __restrict__ seg, const int* __restrict__ desc,
        const int* __restrict__ slot_of, float* __restrict__ out) {
    int d = desc[blockIdx.x];
    if (d < 0) return;
    int e = d >> 16, mt = d & 0xffff;
    int seg0 = seg[e], Te = seg[e + 1] - seg0, m0 = mt * 64;
    __shared__ u16 As[64 * 40];
    int tid = threadIdx.x;
    int lane = tid & 63, wave = tid >> 6;
    int arow = tid >> 2, acol = (tid & 3) * 8;
    bool avalid = (m0 + arow) < Te;
    int kq = lane >> 4, ml = lane & 15;
    int nb = blockIdx.y * 128 + wave * 32;
    const float* wp = w + (size_t)e * NI * NH;
    f32x4 zero = {0.f, 0.f, 0.f, 0.f};
    f32x4 acc[4][2];
#pragma unroll
    for (int i = 0; i < 4; ++i) { acc[i][0] = zero; acc[i][1] = zero; }
    for (int kb = 0; kb < NI; kb += 32) {
        s16x8 av = {0, 0, 0, 0, 0, 0, 0, 0};
        if (avalid) av = *(const s16x8*)(inter + (size_t)(seg0 + m0 + arow) * NI + kb + acol);
        __syncthreads();
        *(s16x8*)&As[arow * 40 + acol] = av;
        __syncthreads();
        s16x8 afr[4];
#pragma unroll
        for (int msi = 0; msi < 4; ++msi)
            afr[msi] = *(const s16x8*)&As[(msi * 16 + ml) * 40 + kq * 8];
        s16x8 bfr[2];
#pragma unroll
        for (int s = 0; s < 2; ++s) {
            const float* bp = wp + (size_t)(kb + kq * 8) * NH + nb + s * 16 + ml;
#pragma unroll
            for (int j = 0; j < 8; ++j) bfr[s][j] = (short)f2bf(bp[(size_t)j * NH]);
        }
#pragma unroll
        for (int msi = 0; msi < 4; ++msi)
#pragma unroll
            for (int s = 0; s < 2; ++s)
                acc[msi][s] = __builtin_amdgcn_mfma_f32_16x16x32_bf16(
                    afr[msi], bfr[s], acc[msi][s], 0, 0, 0);
    }
    float bv[2];
    bv[0] = bias[e * NH + nb + ml];
    bv[1] = bias[e * NH + nb + 16 + ml];
#pragma unroll
    for (int msi = 0; msi < 4; ++msi) {
#pragma unroll
        for (int r = 0; r < 4; ++r) {
            int mrow = m0 + msi * 16 + kq * 4 + r;
            if (mrow < Te) {
                int slot = slot_of[seg0 + mrow];
                int token = slot >> 1;
                float wgt = rw[token * NE + e];
#pragma unroll
                for (int s = 0; s < 2; ++s) {
                    int n = nb + s * 16 + ml;
                    atomicAdd(&out[(size_t)token * NH + n], (acc[msi][s][r] + bv[s]) * wgt);
                }
            }
        }
    }
}

extern "C" void kernel_launch(void* const* d_in, const int* in_sizes, int n_in,
                              void* d_out, int out_size, void* d_ws, size_t ws_size,
                              hipStream_t stream) {
    const float* x   = (const float*)d_in[0];
    const int*   ri  = (const int*)d_in[1];
    const float* rw  = (const float*)d_in[2];
    const float* wgu = (const float*)d_in[3];
    const float* bgu = (const float*)d_in[4];
    const float* wd  = (const float*)d_in[5];
    const float* bd  = (const float*)d_in[6];
    float* out = (float*)d_out;

    char* ws = (char*)d_ws;
    int* seg     = (int*)(ws + WS_SEG);
    int* d64     = (int*)(ws + WS_DESC64);
    int* d128    = (int*)(ws + WS_DESC128);
    int* slot_of = (int*)(ws + WS_SLOT);
    int* pos_of  = (int*)(ws + WS_POS);
    u16* inter   = (u16*)(ws + WS_INTER);

    if (ws_size >= WS_NEED_PIGGY) {
        u16* aReg = (u16*)(ws + WS_AREG);
        u16* wReg = (u16*)(ws + WS_WREG);     // WT_gu
        u16* wtd  = (u16*)(ws + WS_WTD);      // WT_d (disjoint from WT_gu!)
        // launch 1: build + x->bf16 convert + out zero + gate_up weight transpose
        hipLaunchKernelGGL(k_prep, dim3(1 + MTOK + 4096), dim3(256), 0, stream,
                           x, ri, wgu, seg, d64, d128, slot_of, pos_of, aReg, wReg, out);
        // launch 2: gate_up GEMM (x<40) + down weight transpose piggyback (x>=40, dest disjoint)
        hipLaunchKernelGGL(k_gateup_f, dim3(MAXT128 + 64, NGU / 64), dim3(256), 0, stream,
                           aReg, wReg, bgu, seg, d128, slot_of, inter, wd, wtd);
        // launch 3: down GEMM full-K + fused weighted atomic scatter
        hipLaunchKernelGGL(k_down_f, dim3(MAXT128, NH / 64), dim3(256), 0, stream,
                           inter, wtd, bd, rw, seg, d128, slot_of, out);
    } else if (ws_size >= WS_NEED_FAST) {
        u16* aReg = (u16*)(ws + WS_AREG);
        u16* wReg = (u16*)(ws + WS_WREG);
        // launch 1: fused prep
        hipLaunchKernelGGL(k_prep, dim3(1 + MTOK + 4096), dim3(256), 0, stream,
                           x, ri, wgu, seg, d64, d128, slot_of, pos_of, aReg, wReg, out);
        // launch 2: pure gate_up GEMM (no piggyback blocks)
        hipLaunchKernelGGL(k_gateup_f, dim3(MAXT128, NGU / 64), dim3(256), 0, stream,
                           aReg, wReg, bgu, seg, d128, slot_of, inter, wd, wReg);
        // launch 3: down weight transpose (safely overwrites WT_gu, sequential)
        hipLaunchKernelGGL(k_tr, dim3(NH / 64, NI / 64, NE), dim3(256), 0, stream,
                           wd, wReg, NI, NH);
        // launch 4: down GEMM full-K + fused weighted atomic scatter
        hipLaunchKernelGGL(k_down_f, dim3(MAXT128, NH / 64), dim3(256), 0, stream,
                           inter, wReg, bd, rw, seg, d128, slot_of, out);
    } else {
        hipLaunchKernelGGL(k_build, dim3(1), dim3(256), 0, stream, ri, seg, d64, d128,
                           slot_of, pos_of);
        hipMemsetAsync(out, 0, (size_t)MTOK * NH * sizeof(float), stream);
        hipLaunchKernelGGL(k_gateup_s, dim3(MAXT64, NGU / 128), dim3(256), 0, stream,
                           x, wgu, bgu, seg, d64, slot_of, inter);
        hipLaunchKernelGGL(k_down_s, dim3(MAXT64, NH / 128), dim3(256), 0, stream,
                           inter, wd, bd, rw, seg, d64, slot_of, out);
    }
}